// Round 1
// baseline (263.690 us; speedup 1.0000x reference)
//
#include <hip/hip_runtime.h>
#include <cstddef>

// Problem constants
constexpr int B_   = 32;
constexpr int CTX_ = 128;
constexpr int NF_  = 128;     // frames
constexpr int NS_  = 32768;   // samples
constexpr int NE_  = 16;      // events
constexpr int CH_  = 256;
constexpr int WIN_ = 512;
constexpr int NC_  = 257;     // coeffs
constexpr int TC_  = 514;     // 2*coeffs
constexpr int KP_  = 528;     // padded K for irfft gemm (33*16)
constexpr int ROWS_ = B_ * NF_;  // 4096

__device__ __forceinline__ float lrelu(float v) { return v > 0.f ? v : 0.2f * v; }

// ---------------- proj: y0[b][c] = param[b,:] . proj_w[c,:] + proj_b[c] ----------------
__global__ void proj_kernel(const float* __restrict__ param, const float* __restrict__ pw,
                            const float* __restrict__ pb, float* __restrict__ y0) {
    int b = blockIdx.x;      // 32
    int c = threadIdx.x;     // 256
    const float* pr = param + b * CTX_;
    const float* wr = pw + c * CTX_;
    float s = 0.f;
    #pragma unroll 4
    for (int j = 0; j < CTX_; ++j) s += pr[j] * wr[j];
    y0[b * CH_ + c] = s + pb[c];
}

// ---------------- x0[row][c] = y0[b][c] + pos[f][c] ----------------
__global__ void bcast_add_kernel(const float* __restrict__ y0, const float* __restrict__ pos,
                                 float* __restrict__ x0) {
    int idx = blockIdx.x * 256 + threadIdx.x;   // 4096*256
    int c = idx & 255;
    int row = idx >> 8;
    int b = row >> 7, f = row & 127;
    x0[idx] = y0[b * CH_ + c] + pos[f * CH_ + c];
}

// ---------------- generic fp32 tiled GEMM ----------------
// TRANSB=1: C[m][n] = act( sum_k A[m*lda+k] * Bmat[n*ldb+k] + bias[n] )
// TRANSB=0: C[m][n] = act( sum_k A[m*lda+k] * Bmat[k*ldb+n] + bias[n] )
// M multiple of 64; K multiple of 16; N guarded.
template<bool RELU, bool TRANSB>
__global__ __launch_bounds__(256) void gemm_kernel(
    const float* __restrict__ A, const float* __restrict__ Bmat,
    const float* __restrict__ bias, float* __restrict__ C,
    int M, int N, int K, int lda, int ldb, int ldc)
{
    const int tid = threadIdx.x;
    const int tx = tid & 15, ty = tid >> 4;
    const int m0 = blockIdx.y * 64, n0 = blockIdx.x * 64;
    __shared__ float As[16][64];
    __shared__ float Bs[16][64];
    float acc[4][4] = {};
    for (int kt = 0; kt < K; kt += 16) {
        // stage A tile: As[kk][mm]
        {
            int mm = tid >> 2;
            int kk = (tid & 3) * 4;
            const float* src = A + (size_t)(m0 + mm) * lda + kt + kk;
            float4 v = *(const float4*)src;
            As[kk + 0][mm] = v.x; As[kk + 1][mm] = v.y;
            As[kk + 2][mm] = v.z; As[kk + 3][mm] = v.w;
        }
        if (TRANSB) {
            int nn = tid >> 2;
            int kk = (tid & 3) * 4;
            int n = n0 + nn;
            float4 v = make_float4(0.f, 0.f, 0.f, 0.f);
            if (n < N) v = *(const float4*)(Bmat + (size_t)n * ldb + kt + kk);
            Bs[kk + 0][nn] = v.x; Bs[kk + 1][nn] = v.y;
            Bs[kk + 2][nn] = v.z; Bs[kk + 3][nn] = v.w;
        } else {
            int kk = tid >> 4;          // 0..15
            int nn4 = (tid & 15) * 4;   // 0..60
            float4 v = *(const float4*)(Bmat + (size_t)(kt + kk) * ldb + n0 + nn4);
            *(float4*)&Bs[kk][nn4] = v;
        }
        __syncthreads();
        #pragma unroll
        for (int kk = 0; kk < 16; ++kk) {
            float a[4], b[4];
            #pragma unroll
            for (int i = 0; i < 4; ++i) a[i] = As[kk][ty * 4 + i];
            #pragma unroll
            for (int j = 0; j < 4; ++j) b[j] = Bs[kk][tx * 4 + j];
            #pragma unroll
            for (int i = 0; i < 4; ++i)
                #pragma unroll
                for (int j = 0; j < 4; ++j)
                    acc[i][j] += a[i] * b[j];
        }
        __syncthreads();
    }
    #pragma unroll
    for (int i = 0; i < 4; ++i) {
        int m = m0 + ty * 4 + i;
        #pragma unroll
        for (int j = 0; j < 4; ++j) {
            int n = n0 + tx * 4 + j;
            if (n < N) {
                float v = acc[i][j] + (bias ? bias[n] : 0.f);
                if (RELU) v = lrelu(v);
                C[(size_t)m * ldc + n] = v;
            }
        }
    }
}

// ---------------- epilogue: raw (4096x514) -> mags, dphi (4096x257) ----------------
__global__ void epi_kernel(const float* __restrict__ raw, const float* __restrict__ noise,
                           float* __restrict__ mags, float* __restrict__ dphi) {
    int row = blockIdx.x;        // 4096
    int k = threadIdx.x;         // 320, guard
    if (k >= NC_) return;
    const float2* p2 = (const float2*)(raw + (size_t)row * TC_);
    float2 v = p2[k];            // (x0, x1)
    float m = fabsf(v.x);
    float ph = 1.f + v.y * noise[(size_t)row * NC_ + k];
    constexpr float PI = 3.14159265358979323846f;
    mags[(size_t)row * NC_ + k] = m;
    dphi[(size_t)row * NC_ + k] = ph * (float)k * (PI / 256.f);
}

// ---------------- cumsum over frames + cos/sin -> ab (4096 x 528) ----------------
__global__ void cumsum_kernel(const float* __restrict__ mags, const float* __restrict__ dphi,
                              float* __restrict__ ab) {
    int b = blockIdx.x;          // 32
    int k = threadIdx.x;         // 320
    if (k >= NC_) {
        // zero the padded K columns (514..527) so poison/NaN never reaches the GEMM
        if (k < NC_ + 7) {
            int c1 = TC_ + (k - NC_);        // 514..520
            int c2 = TC_ + 7 + (k - NC_);    // 521..527
            for (int f = 0; f < NF_; ++f) {
                size_t ro = (size_t)(b * NF_ + f) * KP_;
                ab[ro + c1] = 0.f;
                ab[ro + c2] = 0.f;
            }
        }
        return;
    }
    float p = 0.f;
    for (int f = 0; f < NF_; ++f) {
        size_t r = (size_t)(b * NF_ + f);
        p += dphi[r * NC_ + k];
        float m = mags[r * NC_ + k];
        float s, c;
        sincosf(p, &s, &c);
        ab[r * KP_ + k] = m * c;
        ab[r * KP_ + NC_ + k] = m * s;
    }
}

// ---------------- irfft table (528 x 512), hann + irfft weights folded in ----------------
__global__ void table_kernel(float* __restrict__ tab) {
    int idx = blockIdx.x * 256 + threadIdx.x;
    if (idx >= KP_ * WIN_) return;
    int k = idx >> 9;
    int n = idx & 511;
    constexpr float PI = 3.14159265358979323846f;
    float val = 0.f;
    float hann = 0.5f * (1.f - cosf((float)n * (PI / 256.f)));
    if (k < NC_) {
        float w = (k == 0 || k == 256) ? 1.f : 2.f;
        int m = (k * n) & 511;
        val = w * (1.f / 512.f) * hann * cosf((float)m * (PI / 256.f));
    } else if (k < TC_) {
        int kk = k - NC_;
        float w = (kk == 0 || kk == 256) ? 1.f : 2.f;
        int m = (kk * n) & 511;
        val = -w * (1.f / 512.f) * hann * sinf((float)m * (PI / 256.f));
    }
    tab[idx] = val;
}

// ---------------- overlap-add: frames (4096x512, windowed) -> sig (32x32768) ----------------
__global__ void ola_kernel(const float* __restrict__ frames, float* __restrict__ sig) {
    int idx = blockIdx.x * 256 + threadIdx.x;   // 32*32768
    int b = idx >> 15;
    int t = idx & (NS_ - 1);
    int q = t >> 8, r = t & 255;
    float v = frames[((size_t)(b * NF_ + q)) * WIN_ + r];
    if (q > 0) v += frames[((size_t)(b * NF_ + q - 1)) * WIN_ + 256 + r];
    sig[idx] = v;
}

// ---------------- sparse conv: out[b,e,t] = sum_k times[b,e,k] * sig[b, t-256k] ----------------
__global__ __launch_bounds__(256) void conv_kernel(const float* __restrict__ sig,
                                                   const float* __restrict__ times,
                                                   float* __restrict__ out) {
    int be = blockIdx.y;         // 0..511  (b*16+e)
    int b = be >> 4;
    __shared__ float ts[NF_];
    if (threadIdx.x < NF_) ts[threadIdx.x] = times[(size_t)be * NF_ + threadIdx.x];
    __syncthreads();
    int t0 = blockIdx.x * 2048;
    float acc[8] = {};
    const float* sg = sig + (size_t)b * NS_;
    for (int k = 0; k < NF_; ++k) {
        float v = ts[k];
        if (v != 0.f) {          // wave-uniform: one-hot -> ~1 active tap
            int base = t0 - (k << 8) + (int)threadIdx.x;
            #pragma unroll
            for (int j = 0; j < 8; ++j) {
                int s = base + j * 256;
                if (s >= 0) acc[j] += v * sg[s];
            }
        }
    }
    float* op = out + (size_t)be * NS_ + t0 + threadIdx.x;
    #pragma unroll
    for (int j = 0; j < 8; ++j) op[j * 256] = acc[j];
}

extern "C" void kernel_launch(void* const* d_in, const int* in_sizes, int n_in,
                              void* d_out, int out_size, void* d_ws, size_t ws_size,
                              hipStream_t stream) {
    const float* param  = (const float*)d_in[0];
    const float* times  = (const float*)d_in[1];
    const float* noise  = (const float*)d_in[2];
    const float* pos    = (const float*)d_in[3];
    const float* proj_w = (const float*)d_in[4];
    const float* proj_b = (const float*)d_in[5];
    const float* w0 = (const float*)d_in[6];
    const float* b0 = (const float*)d_in[7];
    const float* w1 = (const float*)d_in[8];
    const float* b1 = (const float*)d_in[9];
    const float* w2 = (const float*)d_in[10];
    const float* b2 = (const float*)d_in[11];
    const float* w_out = (const float*)d_in[12];
    const float* b_out = (const float*)d_in[13];
    float* out = (float*)d_out;
    float* ws = (float*)d_ws;

    // ws layout (floats), with lifetime-based overlays:
    //  X (2,162,688): RAW (4096x514) then AB (4096x528)
    //  Y (2,105,344): MAGS+DPHI (2x 4096x257) then FRAMES (4096x512)
    //  Z (1,048,576): x0/h2 then SIG
    //  Wb(1,048,576): h1/h3
    float* X   = ws;
    float* Y   = X + (size_t)ROWS_ * KP_;              // 2,162,688
    float* Z   = Y + 2105344;
    float* Wb  = Z + 1048576;
    float* y0  = Wb + 1048576;                          // 8,192
    float* TAB = y0 + 8192;                             // 528*512 = 270,336

    float* RAW  = X;
    float* AB   = X;
    float* MAGS = Y;
    float* DPHI = Y + (size_t)ROWS_ * NC_;
    float* FRAMES = Y;
    float* SIG  = Z;

    // 1) irfft table (independent)
    table_kernel<<<(KP_ * WIN_ + 255) / 256, 256, 0, stream>>>(TAB);
    // 2) proj + broadcast pos
    proj_kernel<<<B_, CH_, 0, stream>>>(param, proj_w, proj_b, y0);
    bcast_add_kernel<<<ROWS_ * CH_ / 256, 256, 0, stream>>>(y0, pos, Z);
    // 3) MLP layers (fp32 GEMM, leaky-relu 0.2)
    dim3 gL(CH_ / 64, ROWS_ / 64);
    gemm_kernel<true, true><<<gL, 256, 0, stream>>>(Z,  w0, b0, Wb, ROWS_, CH_, CH_, CH_, CH_, CH_);
    gemm_kernel<true, true><<<gL, 256, 0, stream>>>(Wb, w1, b1, Z,  ROWS_, CH_, CH_, CH_, CH_, CH_);
    gemm_kernel<true, true><<<gL, 256, 0, stream>>>(Z,  w2, b2, Wb, ROWS_, CH_, CH_, CH_, CH_, CH_);
    // 4) output layer -> RAW (4096 x 514)
    dim3 gO((TC_ + 63) / 64, ROWS_ / 64);
    gemm_kernel<false, true><<<gO, 256, 0, stream>>>(Wb, w_out, b_out, RAW, ROWS_, TC_, CH_, CH_, CH_, TC_);
    // 5) mags / dphi
    epi_kernel<<<ROWS_, 320, 0, stream>>>(RAW, noise, MAGS, DPHI);
    // 6) cumsum over frames + cos/sin -> AB (overlays RAW; pads zeroed)
    cumsum_kernel<<<B_, 320, 0, stream>>>(MAGS, DPHI, AB);
    // 7) irfft+hann as GEMM: FRAMES = AB (4096x528) @ TAB (528x512)
    dim3 gF(WIN_ / 64, ROWS_ / 64);
    gemm_kernel<false, false><<<gF, 256, 0, stream>>>(AB, TAB, nullptr, FRAMES, ROWS_, WIN_, KP_, KP_, WIN_, WIN_);
    // 8) overlap-add -> SIG
    ola_kernel<<<B_ * NS_ / 256, 256, 0, stream>>>(FRAMES, SIG);
    // 9) sparse conv -> out
    dim3 gC(NS_ / 2048, B_ * NE_);
    conv_kernel<<<gC, 256, 0, stream>>>(SIG, times, out);
}

// Round 2
// 218.100 us; speedup vs baseline: 1.2090x; 1.2090x over previous
//
#include <hip/hip_runtime.h>
#include <cstddef>

// Problem constants
constexpr int B_   = 32;
constexpr int CTX_ = 128;
constexpr int NF_  = 128;     // frames
constexpr int NS_  = 32768;   // samples
constexpr int NE_  = 16;      // events
constexpr int CH_  = 256;
constexpr int WIN_ = 512;
constexpr int NC_  = 257;     // coeffs
constexpr int TC_  = 514;     // 2*coeffs
constexpr int KP_  = 528;     // padded K for irfft gemm (33*16)
constexpr int ROWS_ = B_ * NF_;  // 4096
constexpr int CHUNK_ = 8;        // frames per scan chunk
constexpr int NCH_ = NF_ / CHUNK_;  // 16 chunks
constexpr float PI_ = 3.14159265358979323846f;

__device__ __forceinline__ float lrelu(float v) { return v > 0.f ? v : 0.2f * v; }

// ---------------- proj: y0[b][c] = param[b,:] . proj_w[c,:] + proj_b[c] ----------------
__global__ void proj_kernel(const float* __restrict__ param, const float* __restrict__ pw,
                            const float* __restrict__ pb, float* __restrict__ y0) {
    int b = blockIdx.x;      // 32
    int c = threadIdx.x;     // 256
    const float* pr = param + b * CTX_;
    const float* wr = pw + c * CTX_;
    float s = 0.f;
    #pragma unroll 4
    for (int j = 0; j < CTX_; ++j) s += pr[j] * wr[j];
    y0[b * CH_ + c] = s + pb[c];
}

// ---------------- x0[row][c] = y0[b][c] + pos[f][c] ----------------
__global__ void bcast_add_kernel(const float* __restrict__ y0, const float* __restrict__ pos,
                                 float* __restrict__ x0) {
    int idx = blockIdx.x * 256 + threadIdx.x;   // 4096*256
    int c = idx & 255;
    int row = idx >> 8;
    int b = row >> 7, f = row & 127;
    x0[idx] = y0[b * CH_ + c] + pos[f * CH_ + c];
}

// ---------------- generic fp32 tiled GEMM ----------------
// TRANSB=1: C[m][n] = act( sum_k A[m*lda+k] * Bmat[n*ldb+k] + bias[n] )
// TRANSB=0: C[m][n] = act( sum_k A[m*lda+k] * Bmat[k*ldb+n] + bias[n] )
// M multiple of 64; K multiple of 16; N guarded.
template<bool RELU, bool TRANSB>
__global__ __launch_bounds__(256) void gemm_kernel(
    const float* __restrict__ A, const float* __restrict__ Bmat,
    const float* __restrict__ bias, float* __restrict__ C,
    int M, int N, int K, int lda, int ldb, int ldc)
{
    const int tid = threadIdx.x;
    const int tx = tid & 15, ty = tid >> 4;
    const int m0 = blockIdx.y * 64, n0 = blockIdx.x * 64;
    __shared__ float As[16][64];
    __shared__ float Bs[16][64];
    float acc[4][4] = {};
    for (int kt = 0; kt < K; kt += 16) {
        // stage A tile: As[kk][mm]
        {
            int mm = tid >> 2;
            int kk = (tid & 3) * 4;
            const float* src = A + (size_t)(m0 + mm) * lda + kt + kk;
            float4 v = *(const float4*)src;
            As[kk + 0][mm] = v.x; As[kk + 1][mm] = v.y;
            As[kk + 2][mm] = v.z; As[kk + 3][mm] = v.w;
        }
        if (TRANSB) {
            int nn = tid >> 2;
            int kk = (tid & 3) * 4;
            int n = n0 + nn;
            float4 v = make_float4(0.f, 0.f, 0.f, 0.f);
            if (n < N) v = *(const float4*)(Bmat + (size_t)n * ldb + kt + kk);
            Bs[kk + 0][nn] = v.x; Bs[kk + 1][nn] = v.y;
            Bs[kk + 2][nn] = v.z; Bs[kk + 3][nn] = v.w;
        } else {
            int kk = tid >> 4;          // 0..15
            int nn4 = (tid & 15) * 4;   // 0..60
            float4 v = *(const float4*)(Bmat + (size_t)(kt + kk) * ldb + n0 + nn4);
            *(float4*)&Bs[kk][nn4] = v;
        }
        __syncthreads();
        #pragma unroll
        for (int kk = 0; kk < 16; ++kk) {
            float a[4], b[4];
            #pragma unroll
            for (int i = 0; i < 4; ++i) a[i] = As[kk][ty * 4 + i];
            #pragma unroll
            for (int j = 0; j < 4; ++j) b[j] = Bs[kk][tx * 4 + j];
            #pragma unroll
            for (int i = 0; i < 4; ++i)
                #pragma unroll
                for (int j = 0; j < 4; ++j)
                    acc[i][j] += a[i] * b[j];
        }
        __syncthreads();
    }
    #pragma unroll
    for (int i = 0; i < 4; ++i) {
        int m = m0 + ty * 4 + i;
        #pragma unroll
        for (int j = 0; j < 4; ++j) {
            int n = n0 + tx * 4 + j;
            if (n < N) {
                float v = acc[i][j] + (bias ? bias[n] : 0.f);
                if (RELU) v = lrelu(v);
                C[(size_t)m * ldc + n] = v;
            }
        }
    }
}

// ---------------- scan pass 1: per-chunk sum of dphi (double) ----------------
// dphi(row,k) = (1 + raw[row,2k+1]*noise[row,k]) * k * pi/256
__global__ void scan1_kernel(const float* __restrict__ raw, const float* __restrict__ noise,
                             double* __restrict__ sums) {
    int b = blockIdx.x, c = blockIdx.y;
    int k = threadIdx.x;
    if (k >= NC_) return;
    float kf = (float)k * (PI_ / 256.f);
    double s = 0.0;
    #pragma unroll
    for (int j = 0; j < CHUNK_; ++j) {
        int row = b * NF_ + c * CHUNK_ + j;
        float2 v = *(const float2*)(raw + (size_t)row * TC_ + 2 * k);
        float d = (1.f + v.y * noise[(size_t)row * NC_ + k]) * kf;
        s += (double)d;
    }
    sums[((size_t)(b * NCH_ + c)) * NC_ + k] = s;
}

// ---------------- scan pass 2: prefix + replay chunk, sincos, write ab ----------------
__global__ void scan2_kernel(const float* __restrict__ raw, const float* __restrict__ noise,
                             const double* __restrict__ sums, float* __restrict__ ab) {
    int b = blockIdx.x, c = blockIdx.y;
    int k = threadIdx.x;
    if (k >= NC_) {
        // threads 257..270 zero the padded K columns (514..527)
        int pk = k - NC_;
        if (pk < KP_ - TC_) {
            for (int j = 0; j < CHUNK_; ++j) {
                size_t ro = (size_t)(b * NF_ + c * CHUNK_ + j) * KP_;
                ab[ro + TC_ + pk] = 0.f;
            }
        }
        return;
    }
    double p = 0.0;
    for (int cc = 0; cc < c; ++cc)
        p += sums[((size_t)(b * NCH_ + cc)) * NC_ + k];
    float kf = (float)k * (PI_ / 256.f);
    for (int j = 0; j < CHUNK_; ++j) {
        int row = b * NF_ + c * CHUNK_ + j;
        float2 v = *(const float2*)(raw + (size_t)row * TC_ + 2 * k);
        float d = (1.f + v.y * noise[(size_t)row * NC_ + k]) * kf;
        p += (double)d;
        float m = fabsf(v.x);
        float sn, cs;
        sincosf((float)p, &sn, &cs);
        ab[(size_t)row * KP_ + k] = m * cs;
        ab[(size_t)row * KP_ + NC_ + k] = m * sn;
    }
}

// ---------------- irfft table (528 x 512), hann + irfft weights folded in ----------------
__global__ void table_kernel(float* __restrict__ tab) {
    int idx = blockIdx.x * 256 + threadIdx.x;
    if (idx >= KP_ * WIN_) return;
    int k = idx >> 9;
    int n = idx & 511;
    float val = 0.f;
    float hann = 0.5f * (1.f - cosf((float)n * (PI_ / 256.f)));
    if (k < NC_) {
        float w = (k == 0 || k == 256) ? 1.f : 2.f;
        int m = (k * n) & 511;
        val = w * (1.f / 512.f) * hann * cosf((float)m * (PI_ / 256.f));
    } else if (k < TC_) {
        int kk = k - NC_;
        float w = (kk == 0 || kk == 256) ? 1.f : 2.f;
        int m = (kk * n) & 511;
        val = -w * (1.f / 512.f) * hann * sinf((float)m * (PI_ / 256.f));
    }
    tab[idx] = val;
}

// ---------------- overlap-add: frames (4096x512, windowed) -> sig (32x32768) ----------------
__global__ void ola_kernel(const float* __restrict__ frames, float* __restrict__ sig) {
    int idx = blockIdx.x * 256 + threadIdx.x;   // 32*32768
    int b = idx >> 15;
    int t = idx & (NS_ - 1);
    int q = t >> 8, r = t & 255;
    float v = frames[((size_t)(b * NF_ + q)) * WIN_ + r];
    if (q > 0) v += frames[((size_t)(b * NF_ + q - 1)) * WIN_ + 256 + r];
    sig[idx] = v;
}

// ---------------- sparse conv: out[b,e,t] = sum_k times[b,e,k] * sig[b, t-256k] ----------------
__global__ __launch_bounds__(256) void conv_kernel(const float* __restrict__ sig,
                                                   const float* __restrict__ times,
                                                   float* __restrict__ out) {
    int be = blockIdx.y;         // 0..511  (b*16+e)
    int b = be >> 4;
    __shared__ float ts[NF_];
    if (threadIdx.x < NF_) ts[threadIdx.x] = times[(size_t)be * NF_ + threadIdx.x];
    __syncthreads();
    int t0 = blockIdx.x * 2048;
    float acc[8] = {};
    const float* sg = sig + (size_t)b * NS_;
    for (int k = 0; k < NF_; ++k) {
        float v = ts[k];
        if (v != 0.f) {          // wave-uniform: one-hot -> ~1 active tap
            int base = t0 - (k << 8) + (int)threadIdx.x;
            #pragma unroll
            for (int j = 0; j < 8; ++j) {
                int s = base + j * 256;
                if (s >= 0) acc[j] += v * sg[s];
            }
        }
    }
    float* op = out + (size_t)be * NS_ + t0 + threadIdx.x;
    #pragma unroll
    for (int j = 0; j < 8; ++j) op[j * 256] = acc[j];
}

extern "C" void kernel_launch(void* const* d_in, const int* in_sizes, int n_in,
                              void* d_out, int out_size, void* d_ws, size_t ws_size,
                              hipStream_t stream) {
    const float* param  = (const float*)d_in[0];
    const float* times  = (const float*)d_in[1];
    const float* noise  = (const float*)d_in[2];
    const float* pos    = (const float*)d_in[3];
    const float* proj_w = (const float*)d_in[4];
    const float* proj_b = (const float*)d_in[5];
    const float* w0 = (const float*)d_in[6];
    const float* b0 = (const float*)d_in[7];
    const float* w1 = (const float*)d_in[8];
    const float* b1 = (const float*)d_in[9];
    const float* w2 = (const float*)d_in[10];
    const float* b2 = (const float*)d_in[11];
    const float* w_out = (const float*)d_in[12];
    const float* b_out = (const float*)d_in[13];
    float* out = (float*)d_out;
    float* ws = (float*)d_ws;

    // ws layout (floats), lifetime overlays:
    //  R0 (2,105,344): RAW (4096x514), then FRAMES (4096x512) after scan2
    //  R1 (2,162,688): AB (4096x528)
    //  Z  (1,048,576): x0/h2, then SIG
    //  Wb (1,048,576): h1/h3, then SUMS (doubles, 32*16*257*2 = 263,168 floats)
    float* R0  = ws;
    float* R1  = R0 + 2105344;
    float* Z   = R1 + 2162688;
    float* Wb  = Z + 1048576;
    float* y0  = Wb + 1048576;                          // 8,192
    float* TAB = y0 + 8192;                             // 528*512 = 270,336

    float* RAW    = R0;
    float* FRAMES = R0;
    float* AB     = R1;
    float* SIG    = Z;
    double* SUMS  = (double*)Wb;

    // 1) irfft table (independent)
    table_kernel<<<(KP_ * WIN_ + 255) / 256, 256, 0, stream>>>(TAB);
    // 2) proj + broadcast pos
    proj_kernel<<<B_, CH_, 0, stream>>>(param, proj_w, proj_b, y0);
    bcast_add_kernel<<<ROWS_ * CH_ / 256, 256, 0, stream>>>(y0, pos, Z);
    // 3) MLP layers (fp32 GEMM, leaky-relu 0.2)
    dim3 gL(CH_ / 64, ROWS_ / 64);
    gemm_kernel<true, true><<<gL, 256, 0, stream>>>(Z,  w0, b0, Wb, ROWS_, CH_, CH_, CH_, CH_, CH_);
    gemm_kernel<true, true><<<gL, 256, 0, stream>>>(Wb, w1, b1, Z,  ROWS_, CH_, CH_, CH_, CH_, CH_);
    gemm_kernel<true, true><<<gL, 256, 0, stream>>>(Z,  w2, b2, Wb, ROWS_, CH_, CH_, CH_, CH_, CH_);
    // 4) output layer -> RAW (4096 x 514)
    dim3 gO((TC_ + 63) / 64, ROWS_ / 64);
    gemm_kernel<false, true><<<gO, 256, 0, stream>>>(Wb, w_out, b_out, RAW, ROWS_, TC_, CH_, CH_, CH_, TC_);
    // 5) phase scan pass 1: per-chunk dphi sums (double) -> SUMS (overlays dead Wb)
    dim3 gS(B_, NCH_);
    scan1_kernel<<<gS, 320, 0, stream>>>(RAW, noise, SUMS);
    // 6) scan pass 2: prefix + sincos + mags -> AB (pads zeroed)
    scan2_kernel<<<gS, 320, 0, stream>>>(RAW, noise, SUMS, AB);
    // 7) irfft+hann as GEMM: FRAMES = AB (4096x528) @ TAB (528x512); overlays dead RAW
    dim3 gF(WIN_ / 64, ROWS_ / 64);
    gemm_kernel<false, false><<<gF, 256, 0, stream>>>(AB, TAB, nullptr, FRAMES, ROWS_, WIN_, KP_, KP_, WIN_, WIN_);
    // 8) overlap-add -> SIG (overlays dead x0/h2)
    ola_kernel<<<B_ * NS_ / 256, 256, 0, stream>>>(FRAMES, SIG);
    // 9) sparse conv -> out
    dim3 gC(NS_ / 2048, B_ * NE_);
    conv_kernel<<<gC, 256, 0, stream>>>(SIG, times, out);
}

// Round 3
// 188.111 us; speedup vs baseline: 1.4018x; 1.1594x over previous
//
#include <hip/hip_runtime.h>
#include <cstddef>

// Problem constants
constexpr int B_   = 32;
constexpr int CTX_ = 128;
constexpr int NF_  = 128;     // frames
constexpr int NS_  = 32768;   // samples
constexpr int NE_  = 16;      // events
constexpr int CH_  = 256;
constexpr int WIN_ = 512;
constexpr int NC_  = 257;     // coeffs
constexpr int TC_  = 514;     // 2*coeffs
constexpr int KP_  = 528;     // padded K for irfft gemm (33*16)
constexpr int ROWS_ = B_ * NF_;  // 4096
constexpr int CHUNK_ = 8;        // frames per scan chunk
constexpr int NCH_ = NF_ / CHUNK_;  // 16 chunks
constexpr float PI_ = 3.14159265358979323846f;

__device__ __forceinline__ float lrelu(float v) { return v > 0.f ? v : 0.2f * v; }

// ---------------- proj: y0[b][c] = param[b,:] . proj_w[c,:] + proj_b[c] ----------------
__global__ void proj_kernel(const float* __restrict__ param, const float* __restrict__ pw,
                            const float* __restrict__ pb, float* __restrict__ y0) {
    int b = blockIdx.x;      // 32
    int c = threadIdx.x;     // 256
    const float* pr = param + b * CTX_;
    const float* wr = pw + c * CTX_;
    float s = 0.f;
    #pragma unroll 4
    for (int j = 0; j < CTX_; ++j) s += pr[j] * wr[j];
    y0[b * CH_ + c] = s + pb[c];
}

// ---------------- x0[row][c] = y0[b][c] + pos[f][c] ----------------
__global__ void bcast_add_kernel(const float* __restrict__ y0, const float* __restrict__ pos,
                                 float* __restrict__ x0) {
    int idx = blockIdx.x * 256 + threadIdx.x;   // 4096*256
    int c = idx & 255;
    int row = idx >> 8;
    int b = row >> 7, f = row & 127;
    x0[idx] = y0[b * CH_ + c] + pos[f * CH_ + c];
}

// ---------------- generic fp32 tiled GEMM ----------------
template<bool RELU, bool TRANSB>
__global__ __launch_bounds__(256) void gemm_kernel(
    const float* __restrict__ A, const float* __restrict__ Bmat,
    const float* __restrict__ bias, float* __restrict__ C,
    int M, int N, int K, int lda, int ldb, int ldc)
{
    const int tid = threadIdx.x;
    const int tx = tid & 15, ty = tid >> 4;
    const int m0 = blockIdx.y * 64, n0 = blockIdx.x * 64;
    __shared__ float As[16][64];
    __shared__ float Bs[16][64];
    float acc[4][4] = {};
    for (int kt = 0; kt < K; kt += 16) {
        {
            int mm = tid >> 2;
            int kk = (tid & 3) * 4;
            const float* src = A + (size_t)(m0 + mm) * lda + kt + kk;
            float4 v = *(const float4*)src;
            As[kk + 0][mm] = v.x; As[kk + 1][mm] = v.y;
            As[kk + 2][mm] = v.z; As[kk + 3][mm] = v.w;
        }
        if (TRANSB) {
            int nn = tid >> 2;
            int kk = (tid & 3) * 4;
            int n = n0 + nn;
            float4 v = make_float4(0.f, 0.f, 0.f, 0.f);
            if (n < N) v = *(const float4*)(Bmat + (size_t)n * ldb + kt + kk);
            Bs[kk + 0][nn] = v.x; Bs[kk + 1][nn] = v.y;
            Bs[kk + 2][nn] = v.z; Bs[kk + 3][nn] = v.w;
        } else {
            int kk = tid >> 4;          // 0..15
            int nn4 = (tid & 15) * 4;   // 0..60
            float4 v = *(const float4*)(Bmat + (size_t)(kt + kk) * ldb + n0 + nn4);
            *(float4*)&Bs[kk][nn4] = v;
        }
        __syncthreads();
        #pragma unroll
        for (int kk = 0; kk < 16; ++kk) {
            float a[4], b[4];
            #pragma unroll
            for (int i = 0; i < 4; ++i) a[i] = As[kk][ty * 4 + i];
            #pragma unroll
            for (int j = 0; j < 4; ++j) b[j] = Bs[kk][tx * 4 + j];
            #pragma unroll
            for (int i = 0; i < 4; ++i)
                #pragma unroll
                for (int j = 0; j < 4; ++j)
                    acc[i][j] += a[i] * b[j];
        }
        __syncthreads();
    }
    #pragma unroll
    for (int i = 0; i < 4; ++i) {
        int m = m0 + ty * 4 + i;
        #pragma unroll
        for (int j = 0; j < 4; ++j) {
            int n = n0 + tx * 4 + j;
            if (n < N) {
                float v = acc[i][j] + (bias ? bias[n] : 0.f);
                if (RELU) v = lrelu(v);
                C[(size_t)m * ldc + n] = v;
            }
        }
    }
}

// ---------------- scan pass 1: per-chunk sum of dphi (double) ----------------
__global__ void scan1_kernel(const float* __restrict__ raw, const float* __restrict__ noise,
                             double* __restrict__ sums) {
    int b = blockIdx.x, c = blockIdx.y;
    int k = threadIdx.x;
    if (k >= NC_) return;
    float kf = (float)k * (PI_ / 256.f);
    double s = 0.0;
    #pragma unroll
    for (int j = 0; j < CHUNK_; ++j) {
        int row = b * NF_ + c * CHUNK_ + j;
        float2 v = *(const float2*)(raw + (size_t)row * TC_ + 2 * k);
        float d = (1.f + v.y * noise[(size_t)row * NC_ + k]) * kf;
        s += (double)d;
    }
    sums[((size_t)(b * NCH_ + c)) * NC_ + k] = s;
}

// ---------------- scan pass 2: prefix + replay chunk, sincos, write ab ----------------
__global__ void scan2_kernel(const float* __restrict__ raw, const float* __restrict__ noise,
                             const double* __restrict__ sums, float* __restrict__ ab) {
    int b = blockIdx.x, c = blockIdx.y;
    int k = threadIdx.x;
    if (k >= NC_) {
        int pk = k - NC_;
        if (pk < KP_ - TC_) {
            for (int j = 0; j < CHUNK_; ++j) {
                size_t ro = (size_t)(b * NF_ + c * CHUNK_ + j) * KP_;
                ab[ro + TC_ + pk] = 0.f;
            }
        }
        return;
    }
    double p = 0.0;
    for (int cc = 0; cc < c; ++cc)
        p += sums[((size_t)(b * NCH_ + cc)) * NC_ + k];
    float kf = (float)k * (PI_ / 256.f);
    for (int j = 0; j < CHUNK_; ++j) {
        int row = b * NF_ + c * CHUNK_ + j;
        float2 v = *(const float2*)(raw + (size_t)row * TC_ + 2 * k);
        float d = (1.f + v.y * noise[(size_t)row * NC_ + k]) * kf;
        p += (double)d;
        float m = fabsf(v.x);
        float sn, cs;
        sincosf((float)p, &sn, &cs);
        ab[(size_t)row * KP_ + k] = m * cs;
        ab[(size_t)row * KP_ + NC_ + k] = m * sn;
    }
}

// ---------------- irfft table (528 x 512), hann + irfft weights folded in ----------------
__global__ void table_kernel(float* __restrict__ tab) {
    int idx = blockIdx.x * 256 + threadIdx.x;
    if (idx >= KP_ * WIN_) return;
    int k = idx >> 9;
    int n = idx & 511;
    float val = 0.f;
    float hann = 0.5f * (1.f - cosf((float)n * (PI_ / 256.f)));
    if (k < NC_) {
        float w = (k == 0 || k == 256) ? 1.f : 2.f;
        int m = (k * n) & 511;
        val = w * (1.f / 512.f) * hann * cosf((float)m * (PI_ / 256.f));
    } else if (k < TC_) {
        int kk = k - NC_;
        float w = (kk == 0 || kk == 256) ? 1.f : 2.f;
        int m = (kk * n) & 511;
        val = -w * (1.f / 512.f) * hann * sinf((float)m * (PI_ / 256.f));
    }
    tab[idx] = val;
}

// ---------------- overlap-add: frames (4096x512, windowed) -> sig (32x32768) ----------------
__global__ void ola_kernel(const float* __restrict__ frames, float* __restrict__ sig) {
    int idx = blockIdx.x * 256 + threadIdx.x;   // 32*32768
    int b = idx >> 15;
    int t = idx & (NS_ - 1);
    int q = t >> 8, r = t & 255;
    float v = frames[((size_t)(b * NF_ + q)) * WIN_ + r];
    if (q > 0) v += frames[((size_t)(b * NF_ + q - 1)) * WIN_ + 256 + r];
    sig[idx] = v;
}

// ---------------- tap compaction: times (512 x 128, ~one-hot) -> count + (k,amp) list ----------------
__global__ void compact_kernel(const float* __restrict__ times, int* __restrict__ cnt,
                               float2* __restrict__ taps) {
    int be = blockIdx.x;         // 512
    int k = threadIdx.x;         // 128
    __shared__ int c;
    if (k == 0) c = 0;
    __syncthreads();
    float v = times[(size_t)be * NF_ + k];
    if (v != 0.f) {
        int slot = atomicAdd(&c, 1);
        taps[(size_t)be * NF_ + slot] = make_float2((float)k, v);
    }
    __syncthreads();
    if (k == 0) cnt[be] = c;
}

// ---------------- sparse conv (compact taps): out[b,e,t] = sum_i amp_i * sig[b, t-256*k_i] ----------------
__global__ __launch_bounds__(256) void conv_kernel(const float* __restrict__ sig,
                                                   const int* __restrict__ cnt,
                                                   const float2* __restrict__ taps,
                                                   float* __restrict__ out) {
    int be = blockIdx.y;         // 0..511  (b*16+e)
    int b = be >> 4;
    int n = cnt[be];
    int t = blockIdx.x * 2048 + (int)threadIdx.x * 8;
    const float* sg = sig + (size_t)b * NS_;
    float4 a0 = make_float4(0.f, 0.f, 0.f, 0.f);
    float4 a1 = make_float4(0.f, 0.f, 0.f, 0.f);
    for (int i = 0; i < n; ++i) {
        float2 ka = taps[(size_t)be * NF_ + i];
        int s = t - ((int)ka.x << 8);
        float amp = ka.y;
        if (s >= 0) {
            float4 v0 = *(const float4*)(sg + s);
            float4 v1 = *(const float4*)(sg + s + 4);
            a0.x += amp * v0.x; a0.y += amp * v0.y; a0.z += amp * v0.z; a0.w += amp * v0.w;
            a1.x += amp * v1.x; a1.y += amp * v1.y; a1.z += amp * v1.z; a1.w += amp * v1.w;
        }
    }
    float* op = out + (size_t)be * NS_ + t;
    *(float4*)op = a0;
    *(float4*)(op + 4) = a1;
}

extern "C" void kernel_launch(void* const* d_in, const int* in_sizes, int n_in,
                              void* d_out, int out_size, void* d_ws, size_t ws_size,
                              hipStream_t stream) {
    const float* param  = (const float*)d_in[0];
    const float* times  = (const float*)d_in[1];
    const float* noise  = (const float*)d_in[2];
    const float* pos    = (const float*)d_in[3];
    const float* proj_w = (const float*)d_in[4];
    const float* proj_b = (const float*)d_in[5];
    const float* w0 = (const float*)d_in[6];
    const float* b0 = (const float*)d_in[7];
    const float* w1 = (const float*)d_in[8];
    const float* b1 = (const float*)d_in[9];
    const float* w2 = (const float*)d_in[10];
    const float* b2 = (const float*)d_in[11];
    const float* w_out = (const float*)d_in[12];
    const float* b_out = (const float*)d_in[13];
    float* out = (float*)d_out;
    float* ws = (float*)d_ws;

    // ws layout (floats), lifetime overlays:
    //  R0 (2,105,344): RAW (4096x514), then FRAMES (4096x512) after scan2
    //  R1 (2,162,688): AB (4096x528)
    //  Z  (1,048,576): x0/h2, then SIG
    //  Wb (1,048,576): h1/h3, then SUMS (doubles, 32*16*257*2 = 263,168 floats)
    float* R0  = ws;
    float* R1  = R0 + 2105344;
    float* Z   = R1 + 2162688;
    float* Wb  = Z + 1048576;
    float* y0  = Wb + 1048576;                          // 8,192
    float* TAB = y0 + 8192;                             // 528*512 = 270,336
    int*   CNT = (int*)(TAB + 270336);                  // 512
    float2* TAPS = (float2*)(CNT + 512);                // 512*128 float2 = 131,072 floats

    float* RAW    = R0;
    float* FRAMES = R0;
    float* AB     = R1;
    float* SIG    = Z;
    double* SUMS  = (double*)Wb;

    // 0) tap compaction (independent of everything else)
    compact_kernel<<<B_ * NE_, NF_, 0, stream>>>(times, CNT, TAPS);
    // 1) irfft table (independent)
    table_kernel<<<(KP_ * WIN_ + 255) / 256, 256, 0, stream>>>(TAB);
    // 2) proj + broadcast pos
    proj_kernel<<<B_, CH_, 0, stream>>>(param, proj_w, proj_b, y0);
    bcast_add_kernel<<<ROWS_ * CH_ / 256, 256, 0, stream>>>(y0, pos, Z);
    // 3) MLP layers (fp32 GEMM, leaky-relu 0.2)
    dim3 gL(CH_ / 64, ROWS_ / 64);
    gemm_kernel<true, true><<<gL, 256, 0, stream>>>(Z,  w0, b0, Wb, ROWS_, CH_, CH_, CH_, CH_, CH_);
    gemm_kernel<true, true><<<gL, 256, 0, stream>>>(Wb, w1, b1, Z,  ROWS_, CH_, CH_, CH_, CH_, CH_);
    gemm_kernel<true, true><<<gL, 256, 0, stream>>>(Z,  w2, b2, Wb, ROWS_, CH_, CH_, CH_, CH_, CH_);
    // 4) output layer -> RAW (4096 x 514)
    dim3 gO((TC_ + 63) / 64, ROWS_ / 64);
    gemm_kernel<false, true><<<gO, 256, 0, stream>>>(Wb, w_out, b_out, RAW, ROWS_, TC_, CH_, CH_, CH_, TC_);
    // 5) phase scan pass 1: per-chunk dphi sums (double) -> SUMS (overlays dead Wb)
    dim3 gS(B_, NCH_);
    scan1_kernel<<<gS, 320, 0, stream>>>(RAW, noise, SUMS);
    // 6) scan pass 2: prefix + sincos + mags -> AB (pads zeroed)
    scan2_kernel<<<gS, 320, 0, stream>>>(RAW, noise, SUMS, AB);
    // 7) irfft+hann as GEMM: FRAMES = AB (4096x528) @ TAB (528x512); overlays dead RAW
    dim3 gF(WIN_ / 64, ROWS_ / 64);
    gemm_kernel<false, false><<<gF, 256, 0, stream>>>(AB, TAB, nullptr, FRAMES, ROWS_, WIN_, KP_, KP_, WIN_, WIN_);
    // 8) overlap-add -> SIG (overlays dead x0/h2)
    ola_kernel<<<B_ * NS_ / 256, 256, 0, stream>>>(FRAMES, SIG);
    // 9) sparse conv with compact taps -> out
    dim3 gC(NS_ / 2048, B_ * NE_);
    conv_kernel<<<gC, 256, 0, stream>>>(SIG, CNT, TAPS, out);
}

// Round 4
// 151.048 us; speedup vs baseline: 1.7457x; 1.2454x over previous
//
#include <hip/hip_runtime.h>
#include <cstddef>

// Problem constants
constexpr int B_   = 32;
constexpr int CTX_ = 128;
constexpr int NF_  = 128;     // frames
constexpr int NS_  = 32768;   // samples
constexpr int NE_  = 16;      // events
constexpr int CH_  = 256;
constexpr int WIN_ = 512;
constexpr int NC_  = 257;     // coeffs
constexpr int TC_  = 514;     // 2*coeffs
constexpr int ROWS_ = B_ * NF_;  // 4096
constexpr int CHUNK_ = 8;        // frames per scan chunk
constexpr int NCH_ = NF_ / CHUNK_;  // 16 chunks
constexpr int KE_ = 288;         // padded parity-K for irfft gemm (9*32)
constexpr float PI_ = 3.14159265358979323846f;

__device__ __forceinline__ float lrelu(float v) { return v > 0.f ? v : 0.2f * v; }

// ---------------- proj: S[b][c] = param[b,:] . proj_w[c,:] + proj_b[c]  (rows 0..31 of S) ---
__global__ void proj_kernel(const float* __restrict__ param, const float* __restrict__ pw,
                            const float* __restrict__ pb, float* __restrict__ S) {
    int b = blockIdx.x;      // 32
    int c = threadIdx.x;     // 256
    const float* pr = param + b * CTX_;
    const float* wr = pw + c * CTX_;
    float s = 0.f;
    #pragma unroll 4
    for (int j = 0; j < CTX_; ++j) s += pr[j] * wr[j];
    S[b * CH_ + c] = s + pb[c];
}

// ---------------- stack pos into S rows 32..159, zero rows 160..191 ----------------
__global__ void stackpos_kernel(const float* __restrict__ pos, float* __restrict__ S) {
    int idx = blockIdx.x * 256 + threadIdx.x;   // 160*256
    int r = idx >> 8, c = idx & 255;
    float v = (r < NF_) ? pos[r * CH_ + c] : 0.f;
    S[(32 + r) * CH_ + c] = v;
}

// ---------------- gemm2: C = A @ B^T (TRANSB) or A @ B, fp32, 64x64 tile, BK=32 ----------
// M mult of 64, K mult of 32. N guarded on B-load (TRANSB) and C-store.
// blockIdx.z offsets: A += z*sAz, B += z*sBz, C += z*sCz  (K-split or batch).
template<bool TRANSB>
__global__ __launch_bounds__(256) void gemm2(
    const float* __restrict__ A, const float* __restrict__ Bm, float* __restrict__ C,
    int M, int N, int K, int lda, int ldb, int ldc,
    size_t sAz, size_t sBz, size_t sCz)
{
    A  += (size_t)blockIdx.z * sAz;
    Bm += (size_t)blockIdx.z * sBz;
    C  += (size_t)blockIdx.z * sCz;
    const int tid = threadIdx.x;
    const int tx = tid & 15, ty = tid >> 4;
    const int m0 = blockIdx.y * 64, n0 = blockIdx.x * 64;
    __shared__ __align__(16) float As[32][64];
    __shared__ __align__(16) float Bs[32][64];
    const int ar = tid & 63, akg = (tid >> 6) * 8;     // A (and B^T) staging map
    const int bkr = tid >> 4, bc4 = (tid & 15) * 4;    // B (K x N) staging map

    float4 ra0, ra1, rb0, rb1;
    auto loadA = [&](int kt) {
        const float* p = A + (size_t)(m0 + ar) * lda + kt + akg;
        ra0 = *(const float4*)p;
        ra1 = *(const float4*)(p + 4);
    };
    auto loadB = [&](int kt) {
        if (TRANSB) {
            int n = n0 + ar;
            if (n < N) {
                const float* p = Bm + (size_t)n * ldb + kt + akg;
                rb0 = *(const float4*)p;
                rb1 = *(const float4*)(p + 4);
            } else {
                rb0 = make_float4(0.f,0.f,0.f,0.f);
                rb1 = make_float4(0.f,0.f,0.f,0.f);
            }
        } else {
            const float* p = Bm + (size_t)(kt + bkr) * ldb + n0 + bc4;
            rb0 = *(const float4*)p;
            rb1 = *(const float4*)(p + (size_t)16 * ldb);
        }
    };
    loadA(0); loadB(0);
    float acc[4][4] = {};
    for (int kt = 0; kt < K; kt += 32) {
        // regs -> LDS (A transposed to [k][m]; wave writes contiguous m => conflict-free)
        As[akg+0][ar] = ra0.x; As[akg+1][ar] = ra0.y; As[akg+2][ar] = ra0.z; As[akg+3][ar] = ra0.w;
        As[akg+4][ar] = ra1.x; As[akg+5][ar] = ra1.y; As[akg+6][ar] = ra1.z; As[akg+7][ar] = ra1.w;
        if (TRANSB) {
            Bs[akg+0][ar] = rb0.x; Bs[akg+1][ar] = rb0.y; Bs[akg+2][ar] = rb0.z; Bs[akg+3][ar] = rb0.w;
            Bs[akg+4][ar] = rb1.x; Bs[akg+5][ar] = rb1.y; Bs[akg+6][ar] = rb1.z; Bs[akg+7][ar] = rb1.w;
        } else {
            *(float4*)&Bs[bkr][bc4] = rb0;
            *(float4*)&Bs[bkr+16][bc4] = rb1;
        }
        __syncthreads();
        if (kt + 32 < K) { loadA(kt + 32); loadB(kt + 32); }
        #pragma unroll
        for (int kk = 0; kk < 32; ++kk) {
            float4 av = *(const float4*)&As[kk][ty*4];
            float4 bv = *(const float4*)&Bs[kk][tx*4];
            float a4[4] = {av.x, av.y, av.z, av.w};
            float b4[4] = {bv.x, bv.y, bv.z, bv.w};
            #pragma unroll
            for (int i = 0; i < 4; ++i)
                #pragma unroll
                for (int j = 0; j < 4; ++j)
                    acc[i][j] += a4[i] * b4[j];
        }
        __syncthreads();
    }
    if (((ldc & 3) == 0) && n0 + 64 <= N) {
        #pragma unroll
        for (int i = 0; i < 4; ++i) {
            float4 st = make_float4(acc[i][0], acc[i][1], acc[i][2], acc[i][3]);
            *(float4*)&C[(size_t)(m0 + ty*4 + i) * ldc + n0 + tx*4] = st;
        }
    } else {
        #pragma unroll
        for (int i = 0; i < 4; ++i)
            #pragma unroll
            for (int j = 0; j < 4; ++j) {
                int n = n0 + tx*4 + j;
                if (n < N) C[(size_t)(m0 + ty*4 + i) * ldc + n] = acc[i][j];
            }
    }
}

// ---------------- fuse1: h1 = lrelu(YP[b] + YP[32+f] + b0) ----------------
__global__ void fuse1_kernel(const float* __restrict__ YP, const float* __restrict__ b0,
                             float* __restrict__ dst) {
    int idx = blockIdx.x * 256 + threadIdx.x;   // 4096*256
    int c = idx & 255;
    int row = idx >> 8;
    int b = row >> 7, f = row & 127;
    dst[idx] = lrelu(YP[b * CH_ + c] + YP[(32 + f) * CH_ + c] + b0[c]);
}

// ---------------- fuse2: h = lrelu(P0 + P1 + bias) over 4096x256 ----------------
__global__ void fuse2_kernel(const float* __restrict__ P, const float* __restrict__ bias,
                             float* __restrict__ dst) {
    int idx = blockIdx.x * 256 + threadIdx.x;
    dst[idx] = lrelu(P[idx] + P[idx + ROWS_ * CH_] + bias[idx & 255]);
}

// ---------------- fuseOUT: RAW = P0 + P1 + b_out over 4096x514 (partial ld 576) --------
__global__ void fuseout_kernel(const float* __restrict__ P, const float* __restrict__ bo,
                               float* __restrict__ raw) {
    int row = blockIdx.x;          // 4096
    for (int n = threadIdx.x; n < TC_; n += 256) {
        raw[(size_t)row * TC_ + n] =
            P[(size_t)row * 576 + n] + P[(size_t)ROWS_ * 576 + (size_t)row * 576 + n] + bo[n];
    }
}

// ---------------- scan pass 1: per-chunk sum of dphi (double) ----------------
__global__ void scan1_kernel(const float* __restrict__ raw, const float* __restrict__ noise,
                             double* __restrict__ sums) {
    int b = blockIdx.x, c = blockIdx.y;
    int k = threadIdx.x;
    if (k >= NC_) return;
    float kf = (float)k * (PI_ / 256.f);
    double s = 0.0;
    #pragma unroll
    for (int j = 0; j < CHUNK_; ++j) {
        int row = b * NF_ + c * CHUNK_ + j;
        float2 v = *(const float2*)(raw + (size_t)row * TC_ + 2 * k);
        float d = (1.f + v.y * noise[(size_t)row * NC_ + k]) * kf;
        s += (double)d;
    }
    sums[((size_t)(b * NCH_ + c)) * NC_ + k] = s;
}

// ---------------- scan pass 2: prefix + sincos, write parity-split AB_e / AB_o ---------
// coefficient k: cos val -> (k even ? ABe[.., k>>1] : ABo[.., k>>1])
//               sin val -> (k even ? ABe[.., 129 + (k>>1)] : ABo[.., 128 + (k>>1)])
__global__ void scan2_kernel(const float* __restrict__ raw, const float* __restrict__ noise,
                             const double* __restrict__ sums,
                             float* __restrict__ ABe, float* __restrict__ ABo) {
    int b = blockIdx.x, c = blockIdx.y;
    int k = threadIdx.x;
    if (k >= NC_) {
        int pk = k - NC_;   // 0..62
        for (int j = 0; j < CHUNK_; ++j) {
            size_t row = (size_t)(b * NF_ + c * CHUNK_ + j);
            if (pk < KE_ - 258) ABe[row * KE_ + 258 + pk] = 0.f;
            if (pk < KE_ - 256) ABo[row * KE_ + 256 + pk] = 0.f;
        }
        return;
    }
    double p = 0.0;
    for (int cc = 0; cc < c; ++cc)
        p += sums[((size_t)(b * NCH_ + cc)) * NC_ + k];
    float kf = (float)k * (PI_ / 256.f);
    int half = k >> 1;
    bool even = (k & 1) == 0;
    int ccol = half;
    int scol = even ? (129 + half) : (128 + half);
    float* dst = even ? ABe : ABo;
    for (int j = 0; j < CHUNK_; ++j) {
        int row = b * NF_ + c * CHUNK_ + j;
        float2 v = *(const float2*)(raw + (size_t)row * TC_ + 2 * k);
        float d = (1.f + v.y * noise[(size_t)row * NC_ + k]) * kf;
        p += (double)d;
        float m = fabsf(v.x);
        float sn, cs;
        sincosf((float)p, &sn, &cs);
        dst[(size_t)row * KE_ + ccol] = m * cs;
        dst[(size_t)row * KE_ + scol] = m * sn;
    }
}

// ---------------- parity irfft tables T_e, T_o (288 x 256 each), no hann ----------------
__global__ void table2_kernel(float* __restrict__ Te, float* __restrict__ To) {
    int idx = blockIdx.x * 256 + threadIdx.x;
    if (idx >= 2 * KE_ * 256) return;
    int z = idx / (KE_ * 256);
    int rr = idx - z * (KE_ * 256);
    int j = rr >> 8;
    int n = rr & 255;
    float val = 0.f;
    if (z == 0) {  // even frequencies
        if (j < 129) {
            int k = 2 * j;
            float w = (k == 0 || k == 256) ? 1.f : 2.f;
            int m = (k * n) & 511;
            val = w * (1.f / 512.f) * cosf((float)m * (PI_ / 256.f));
        } else if (j < 258) {
            int kk = 2 * (j - 129);
            float w = (kk == 0 || kk == 256) ? 1.f : 2.f;
            int m = (kk * n) & 511;
            val = -w * (1.f / 512.f) * sinf((float)m * (PI_ / 256.f));
        }
        Te[(size_t)j * 256 + n] = val;
    } else {       // odd frequencies (weight always 2)
        if (j < 128) {
            int k = 2 * j + 1;
            int m = (k * n) & 511;
            val = 2.f * (1.f / 512.f) * cosf((float)m * (PI_ / 256.f));
        } else if (j < 256) {
            int kk = 2 * (j - 128) + 1;
            int m = (kk * n) & 511;
            val = -2.f * (1.f / 512.f) * sinf((float)m * (PI_ / 256.f));
        }
        To[(size_t)j * 256 + n] = val;
    }
}

// ---------------- overlap-add with hann + parity combine: E,O (4096x256) -> sig --------
__global__ void ola2_kernel(const float* __restrict__ E, const float* __restrict__ O,
                            float* __restrict__ sig) {
    int idx = blockIdx.x * 256 + threadIdx.x;   // 32*32768
    int b = idx >> 15;
    int t = idx & (NS_ - 1);
    int q = t >> 8, r = t & 255;
    float c = cosf((float)r * (PI_ / 256.f));
    float hr  = 0.5f - 0.5f * c;   // hann[r]
    float hr2 = 0.5f + 0.5f * c;   // hann[256+r]
    size_t row = (size_t)(b * NF_ + q) * 256 + r;
    float v = hr * (E[row] + O[row]);
    if (q > 0) v += hr2 * (E[row - 256] - O[row - 256]);
    sig[idx] = v;
}

// ---------------- tap compaction: times (512 x 128, one-hot) -> count + (k,amp) --------
__global__ void compact_kernel(const float* __restrict__ times, int* __restrict__ cnt,
                               float2* __restrict__ taps) {
    int be = blockIdx.x;         // 512
    int k = threadIdx.x;         // 128
    __shared__ int c;
    if (k == 0) c = 0;
    __syncthreads();
    float v = times[(size_t)be * NF_ + k];
    if (v != 0.f) {
        int slot = atomicAdd(&c, 1);
        taps[(size_t)be * NF_ + slot] = make_float2((float)k, v);
    }
    __syncthreads();
    if (k == 0) cnt[be] = c;
}

// ---------------- sparse conv (compact taps) ----------------
__global__ __launch_bounds__(256) void conv_kernel(const float* __restrict__ sig,
                                                   const int* __restrict__ cnt,
                                                   const float2* __restrict__ taps,
                                                   float* __restrict__ out) {
    int be = blockIdx.y;         // 0..511  (b*16+e)
    int b = be >> 4;
    int n = cnt[be];
    int t = blockIdx.x * 2048 + (int)threadIdx.x * 8;
    const float* sg = sig + (size_t)b * NS_;
    float4 a0 = make_float4(0.f, 0.f, 0.f, 0.f);
    float4 a1 = make_float4(0.f, 0.f, 0.f, 0.f);
    for (int i = 0; i < n; ++i) {
        float2 ka = taps[(size_t)be * NF_ + i];
        int s = t - ((int)ka.x << 8);
        float amp = ka.y;
        if (s >= 0) {
            float4 v0 = *(const float4*)(sg + s);
            float4 v1 = *(const float4*)(sg + s + 4);
            a0.x += amp * v0.x; a0.y += amp * v0.y; a0.z += amp * v0.z; a0.w += amp * v0.w;
            a1.x += amp * v1.x; a1.y += amp * v1.y; a1.z += amp * v1.z; a1.w += amp * v1.w;
        }
    }
    float* op = out + (size_t)be * NS_ + t;
    *(float4*)op = a0;
    *(float4*)(op + 4) = a1;
}

extern "C" void kernel_launch(void* const* d_in, const int* in_sizes, int n_in,
                              void* d_out, int out_size, void* d_ws, size_t ws_size,
                              hipStream_t stream) {
    const float* param  = (const float*)d_in[0];
    const float* times  = (const float*)d_in[1];
    const float* noise  = (const float*)d_in[2];
    const float* pos    = (const float*)d_in[3];
    const float* proj_w = (const float*)d_in[4];
    const float* proj_b = (const float*)d_in[5];
    const float* w0 = (const float*)d_in[6];
    const float* b0 = (const float*)d_in[7];
    const float* w1 = (const float*)d_in[8];
    const float* b1 = (const float*)d_in[9];
    const float* w2 = (const float*)d_in[10];
    const float* b2 = (const float*)d_in[11];
    const float* w_out = (const float*)d_in[12];
    const float* b_out = (const float*)d_in[13];
    float* out = (float*)d_out;
    float* ws = (float*)d_ws;

    // ws layout (float offsets), no risky overlays (ws is ~268 MB)
    float* S    = ws;                       // 192*256      = 49,152
    float* YP   = S    + 49152;             // 192*256      = 49,152
    float* H_A  = YP   + 49152;             // 4096*256     = 1,048,576
    float* H_B  = H_A  + 1048576;           // 4096*256     = 1,048,576
    float* PART = H_B  + 1048576;           // 2*4096*576   = 4,718,592
    float* RAW  = PART + 4718592;           // 4096*514     = 2,105,344
    float* ABe  = RAW  + 2105344;           // 4096*288     = 1,179,648
    float* ABo  = ABe  + 1179648;           // 4096*288     = 1,179,648
    float* Te   = ABo  + 1179648;           // 288*256      = 73,728
    float* To   = Te   + 73728;             // 288*256      = 73,728
    float* EO   = To   + 73728;             // 2*4096*256   = 2,097,152  (E then O)
    float* SIG  = EO   + 2097152;           // 32*32768     = 1,048,576
    double* SUMS = (double*)(SIG + 1048576);// 32*16*257 dbl = 263,168 floats
    int*   CNT  = (int*)(SIG + 1048576 + 263168);   // 512
    float2* TAPS = (float2*)(CNT + 512);            // 512*128*2 floats

    // 1) parity irfft tables + tap compaction (independent)
    table2_kernel<<<(2 * KE_ * 256 + 255) / 256, 256, 0, stream>>>(Te, To);
    compact_kernel<<<B_ * NE_, NF_, 0, stream>>>(times, CNT, TAPS);
    // 2) proj -> S rows 0..31; pos -> S rows 32..159; zero 160..191
    proj_kernel<<<B_, CH_, 0, stream>>>(param, proj_w, proj_b, S);
    stackpos_kernel<<<160, 256, 0, stream>>>(pos, S);
    // 3) layer-1 collapse: YP = S @ w0^T (192x256x256)
    gemm2<true><<<dim3(4, 3, 1), 256, 0, stream>>>(S, w0, YP, 192, CH_, CH_, CH_, CH_, CH_, 0, 0, 0);
    fuse1_kernel<<<ROWS_ * CH_ / 256, 256, 0, stream>>>(YP, b0, H_A);
    // 4) layers 2,3 with K-split 2 (grid.z=2), partials -> PART, fuse adds bias+lrelu
    gemm2<true><<<dim3(4, 64, 2), 256, 0, stream>>>(H_A, w1, PART, ROWS_, CH_, 128, CH_, CH_, CH_,
                                                    128, 128, (size_t)ROWS_ * CH_);
    fuse2_kernel<<<ROWS_ * CH_ / 256, 256, 0, stream>>>(PART, b1, H_B);
    gemm2<true><<<dim3(4, 64, 2), 256, 0, stream>>>(H_B, w2, PART, ROWS_, CH_, 128, CH_, CH_, CH_,
                                                    128, 128, (size_t)ROWS_ * CH_);
    fuse2_kernel<<<ROWS_ * CH_ / 256, 256, 0, stream>>>(PART, b2, H_A);
    // 5) output layer (N=514, partial ldc=576), K-split 2 -> PART; fuse -> RAW
    gemm2<true><<<dim3(9, 64, 2), 256, 0, stream>>>(H_A, w_out, PART, ROWS_, TC_, 128, CH_, CH_, 576,
                                                    128, 128, (size_t)ROWS_ * 576);
    fuseout_kernel<<<ROWS_, 256, 0, stream>>>(PART, b_out, RAW);
    // 6) phase scan (double-precision carry)
    dim3 gS(B_, NCH_);
    scan1_kernel<<<gS, 320, 0, stream>>>(RAW, noise, SUMS);
    scan2_kernel<<<gS, 320, 0, stream>>>(RAW, noise, SUMS, ABe, ABo);
    // 7) parity irfft: z=0: E = ABe@Te, z=1: O = ABo@To (TRANSB=0, batched via z)
    gemm2<false><<<dim3(4, 64, 2), 256, 0, stream>>>(ABe, Te, EO, ROWS_, 256, KE_, KE_, 256, 256,
                                                     (size_t)ROWS_ * KE_, (size_t)KE_ * 256,
                                                     (size_t)ROWS_ * 256);
    // 8) overlap-add + hann + parity combine -> SIG
    ola2_kernel<<<B_ * NS_ / 256, 256, 0, stream>>>(EO, EO + (size_t)ROWS_ * 256, SIG);
    // 9) sparse conv -> out
    dim3 gC(NS_ / 2048, B_ * NE_);
    conv_kernel<<<gC, 256, 0, stream>>>(SIG, CNT, TAPS, out);
}

// Round 6
// 130.724 us; speedup vs baseline: 2.0171x; 1.1555x over previous
//
#include <hip/hip_runtime.h>
#include <cstddef>

typedef unsigned short u16;
typedef __bf16 bf16x8 __attribute__((ext_vector_type(8)));
typedef float f32x4 __attribute__((ext_vector_type(4)));

// Problem constants
constexpr int B_   = 32;
constexpr int CTX_ = 128;
constexpr int NF_  = 128;     // frames
constexpr int NS_  = 32768;   // samples
constexpr int NE_  = 16;      // events
constexpr int CH_  = 256;
constexpr int NC_  = 257;     // coeffs
constexpr int TC_  = 514;     // 2*coeffs
constexpr int ROWS_ = B_ * NF_;  // 4096
constexpr int CHUNK_ = 8;        // frames per scan chunk
constexpr int NCH_ = NF_ / CHUNK_;  // 16 chunks
constexpr int KE_ = 288;         // parity-K for irfft (content 258/256, padded)
constexpr int K3MLP_ = 768;      // 3*256
constexpr int K3IR_ = 896;       // 3*288=864, padded to 64-mult
constexpr float PI_ = 3.14159265358979323846f;

__device__ __forceinline__ float lrelu(float v) { return v > 0.f ? v : 0.2f * v; }
__device__ __forceinline__ u16 f2bf(float x) {
    unsigned u = __float_as_uint(x);
    return (u16)((u + 0x7FFFu + ((u >> 16) & 1u)) >> 16);
}
__device__ __forceinline__ float bf2f(u16 h) { return __uint_as_float(((unsigned)h) << 16); }

// ---------------- proj: S[b][c] = param[b,:] . proj_w[c,:] + proj_b[c] ----------------
__global__ void proj_kernel(const float* __restrict__ param, const float* __restrict__ pw,
                            const float* __restrict__ pb, float* __restrict__ S) {
    int b = blockIdx.x;      // 32
    int c = threadIdx.x;     // 256
    const float* pr = param + b * CTX_;
    const float* wr = pw + c * CTX_;
    float s = 0.f;
    #pragma unroll 4
    for (int j = 0; j < CTX_; ++j) s += pr[j] * wr[j];
    S[b * CH_ + c] = s + pb[c];
}

// ---------------- stack pos into S rows 32..159, zero rows 160..191 ----------------
__global__ void stackpos_kernel(const float* __restrict__ pos, float* __restrict__ S) {
    int idx = blockIdx.x * 256 + threadIdx.x;   // 160*256
    int r = idx >> 8, c = idx & 255;
    float v = (r < NF_) ? pos[r * CH_ + c] : 0.f;
    S[(32 + r) * CH_ + c] = v;
}

// ---------------- fp32 gemm (layer-1 only): C = A @ B^T, 64x64 tile, BK=32 ----------
__global__ __launch_bounds__(256) void gemm2(
    const float* __restrict__ A, const float* __restrict__ Bm, float* __restrict__ C,
    int M, int N, int K, int lda, int ldb, int ldc)
{
    const int tid = threadIdx.x;
    const int tx = tid & 15, ty = tid >> 4;
    const int m0 = blockIdx.y * 64, n0 = blockIdx.x * 64;
    __shared__ __align__(16) float As[32][64];
    __shared__ __align__(16) float Bs[32][64];
    const int ar = tid & 63, akg = (tid >> 6) * 8;
    float4 ra0, ra1, rb0, rb1;
    auto loadA = [&](int kt) {
        const float* p = A + (size_t)(m0 + ar) * lda + kt + akg;
        ra0 = *(const float4*)p; ra1 = *(const float4*)(p + 4);
    };
    auto loadB = [&](int kt) {
        const float* p = Bm + (size_t)(n0 + ar) * ldb + kt + akg;
        rb0 = *(const float4*)p; rb1 = *(const float4*)(p + 4);
    };
    loadA(0); loadB(0);
    float acc[4][4] = {};
    for (int kt = 0; kt < K; kt += 32) {
        As[akg+0][ar] = ra0.x; As[akg+1][ar] = ra0.y; As[akg+2][ar] = ra0.z; As[akg+3][ar] = ra0.w;
        As[akg+4][ar] = ra1.x; As[akg+5][ar] = ra1.y; As[akg+6][ar] = ra1.z; As[akg+7][ar] = ra1.w;
        Bs[akg+0][ar] = rb0.x; Bs[akg+1][ar] = rb0.y; Bs[akg+2][ar] = rb0.z; Bs[akg+3][ar] = rb0.w;
        Bs[akg+4][ar] = rb1.x; Bs[akg+5][ar] = rb1.y; Bs[akg+6][ar] = rb1.z; Bs[akg+7][ar] = rb1.w;
        __syncthreads();
        if (kt + 32 < K) { loadA(kt + 32); loadB(kt + 32); }
        #pragma unroll
        for (int kk = 0; kk < 32; ++kk) {
            float4 av = *(const float4*)&As[kk][ty*4];
            float4 bv = *(const float4*)&Bs[kk][tx*4];
            float a4[4] = {av.x, av.y, av.z, av.w};
            float b4[4] = {bv.x, bv.y, bv.z, bv.w};
            #pragma unroll
            for (int i = 0; i < 4; ++i)
                #pragma unroll
                for (int j = 0; j < 4; ++j)
                    acc[i][j] += a4[i] * b4[j];
        }
        __syncthreads();
    }
    #pragma unroll
    for (int i = 0; i < 4; ++i)
        #pragma unroll
        for (int j = 0; j < 4; ++j)
            C[(size_t)(m0 + ty*4 + i) * ldc + n0 + tx*4 + j] = acc[i][j];
}

// ---------------- fuse1: H1_3 triplet = lrelu(YP[b] + YP[32+f] + b0) ----------------
__global__ void fuse1_kernel(const float* __restrict__ YP, const float* __restrict__ b0,
                             u16* __restrict__ H3) {
    int idx = blockIdx.x * 256 + threadIdx.x;   // 4096*256
    int c = idx & 255;
    int row = idx >> 8;
    int b = row >> 7, f = row & 127;
    float v = lrelu(YP[b * CH_ + c] + YP[(32 + f) * CH_ + c] + b0[c]);
    u16 h = f2bf(v), lo = f2bf(v - bf2f(h));
    u16* p = H3 + (size_t)row * K3MLP_;
    p[c] = h; p[256 + c] = lo; p[512 + c] = h;
}

// ---------------- weight conversion: w [N][256] fp32 -> B3t [Npad][768] (hi|hi|lo) ----
__global__ void wconv_kernel(const float* __restrict__ w, u16* __restrict__ B3,
                             int N, int Npad) {
    int idx = blockIdx.x * 256 + threadIdx.x;
    if (idx >= Npad * 256) return;
    int n = idx >> 8, k = idx & 255;
    float v = (n < N) ? w[n * 256 + k] : 0.f;
    u16 h = f2bf(v), lo = f2bf(v - bf2f(h));
    u16* p = B3 + (size_t)n * K3MLP_;
    p[k] = h; p[256 + k] = h; p[512 + k] = lo;
}

// ---------------- mfgemm: C = A3 @ B3^T, bf16-split MFMA, 64x64 tile, BK=64 ----------
// EPI 0: bias+lrelu -> bf16 triplet (ldc=768, hi|lo|hi at n, 256+n, 512+n)
// EPI 1: bias -> fp32 (N-guarded)
// EPI 2: plain fp32
template<int EPI>
__global__ __launch_bounds__(256) void mfgemm(
    const u16* __restrict__ A3, const u16* __restrict__ B3,
    const float* __restrict__ bias, void* __restrict__ Cout,
    int N, int K3, int lda, int ldb, int ldc,
    size_t sAz, size_t sBz, size_t sCz)
{
    A3 += (size_t)blockIdx.z * sAz;
    B3 += (size_t)blockIdx.z * sBz;
    const int tid = threadIdx.x;
    const int m0 = blockIdx.y * 64, n0 = blockIdx.x * 64;
    __shared__ __align__(16) u16 Als[64 * 64];
    __shared__ __align__(16) u16 Bls[64 * 64];
    // staging: thread -> row (tid>>2), 32B chunk ((tid&3)*32B), XOR-swizzled LDS store
    const int sr = tid >> 2;
    const int sc = (tid & 3) * 16;                 // ushort offset
    const u16* ga = A3 + (size_t)(m0 + sr) * lda + sc;
    const u16* gb = B3 + (size_t)(n0 + sr) * ldb + sc;
    const int xr = (sr & 7) << 4;
    char* la0 = (char*)Als + sr * 128 + ((sc * 2) ^ xr);
    char* la1 = (char*)Als + sr * 128 + ((sc * 2 + 16) ^ xr);
    char* lb0 = (char*)Bls + sr * 128 + ((sc * 2) ^ xr);
    char* lb1 = (char*)Bls + sr * 128 + ((sc * 2 + 16) ^ xr);
    // fragment maps: 4 waves, each 32x32 (2x2 frags of 16x16)
    const int wv = tid >> 6, lane = tid & 63;
    const int wr = (wv >> 1) * 32, wc = (wv & 1) * 32;
    const int lr = lane & 15;
    const int lkb = (lane >> 4) * 16;              // byte offset of 8-bf16 group
    const int xf = (lr & 7) << 4;
    const char* lsa0 = (const char*)Als + (wr + lr) * 128;
    const char* lsa1 = (const char*)Als + (wr + 16 + lr) * 128;
    const char* lsb0 = (const char*)Bls + (wc + lr) * 128;
    const char* lsb1 = (const char*)Bls + (wc + 16 + lr) * 128;
    f32x4 acc00 = {0.f, 0.f, 0.f, 0.f}, acc01 = acc00, acc10 = acc00, acc11 = acc00;
    for (int kt = 0; kt < K3; kt += 64) {
        uint4 va0 = *(const uint4*)(ga + kt);
        uint4 va1 = *(const uint4*)(ga + kt + 8);
        uint4 vb0 = *(const uint4*)(gb + kt);
        uint4 vb1 = *(const uint4*)(gb + kt + 8);
        __syncthreads();
        *(uint4*)la0 = va0; *(uint4*)la1 = va1;
        *(uint4*)lb0 = vb0; *(uint4*)lb1 = vb1;
        __syncthreads();
        #pragma unroll
        for (int s = 0; s < 2; ++s) {
            int kb = (s * 64 + lkb) ^ xf;
            bf16x8 a0 = *(const bf16x8*)(lsa0 + kb);
            bf16x8 a1 = *(const bf16x8*)(lsa1 + kb);
            bf16x8 b0 = *(const bf16x8*)(lsb0 + kb);
            bf16x8 b1 = *(const bf16x8*)(lsb1 + kb);
            acc00 = __builtin_amdgcn_mfma_f32_16x16x32_bf16(a0, b0, acc00, 0, 0, 0);
            acc01 = __builtin_amdgcn_mfma_f32_16x16x32_bf16(a0, b1, acc01, 0, 0, 0);
            acc10 = __builtin_amdgcn_mfma_f32_16x16x32_bf16(a1, b0, acc10, 0, 0, 0);
            acc11 = __builtin_amdgcn_mfma_f32_16x16x32_bf16(a1, b1, acc11, 0, 0, 0);
        }
    }
    // epilogue: D[row=(lane>>4)*4+r][col=lane&15] per frag
    const int er = (lane >> 4) * 4;
    const int ec = lane & 15;
    auto emit = [&](const f32x4& A, int mi, int ni) {
        #pragma unroll
        for (int r = 0; r < 4; ++r) {
            int m = m0 + wr + mi * 16 + er + r;
            int n = n0 + wc + ni * 16 + ec;
            float v = A[r];
            if (EPI == 0) {
                v = lrelu(v + bias[n]);
                u16 h = f2bf(v), lo = f2bf(v - bf2f(h));
                u16* p = (u16*)Cout + (size_t)m * ldc + n;
                p[0] = h; p[256] = lo; p[512] = h;
            } else if (EPI == 1) {
                if (n < N) ((float*)Cout)[(size_t)m * ldc + n] = v + bias[n];
            } else {
                float* cf = (float*)Cout + (size_t)blockIdx.z * sCz;
                cf[(size_t)m * ldc + n] = v;
            }
        }
    };
    emit(acc00, 0, 0); emit(acc01, 0, 1); emit(acc10, 1, 0); emit(acc11, 1, 1);
}

// ---------------- scan pass 1: per-chunk sum of dphi (double) ----------------
__global__ void scan1_kernel(const float* __restrict__ raw, const float* __restrict__ noise,
                             double* __restrict__ sums) {
    int b = blockIdx.x, c = blockIdx.y;
    int k = threadIdx.x;
    if (k >= NC_) return;
    float kf = (float)k * (PI_ / 256.f);
    double s = 0.0;
    #pragma unroll
    for (int j = 0; j < CHUNK_; ++j) {
        int row = b * NF_ + c * CHUNK_ + j;
        float2 v = *(const float2*)(raw + (size_t)row * TC_ + 2 * k);
        float d = (1.f + v.y * noise[(size_t)row * NC_ + k]) * kf;
        s += (double)d;
    }
    sums[((size_t)(b * NCH_ + c)) * NC_ + k] = s;
}

// ---------------- scan pass 2: prefix + sincos, write parity triplet AB3e/AB3o --------
__global__ void scan2_kernel(const float* __restrict__ raw, const float* __restrict__ noise,
                             const double* __restrict__ sums,
                             u16* __restrict__ AB3e, u16* __restrict__ AB3o) {
    int b = blockIdx.x, c = blockIdx.y;
    int k = threadIdx.x;
    if (k >= NC_) return;
    double p = 0.0;
    for (int cc = 0; cc < c; ++cc)
        p += sums[((size_t)(b * NCH_ + cc)) * NC_ + k];
    float kf = (float)k * (PI_ / 256.f);
    int half = k >> 1;
    bool even = (k & 1) == 0;
    int ccol = half;
    int scol = even ? (129 + half) : (128 + half);
    u16* dst = even ? AB3e : AB3o;
    for (int j = 0; j < CHUNK_; ++j) {
        int row = b * NF_ + c * CHUNK_ + j;
        float2 v = *(const float2*)(raw + (size_t)row * TC_ + 2 * k);
        float d = (1.f + v.y * noise[(size_t)row * NC_ + k]) * kf;
        p += (double)d;
        float m = fabsf(v.x);
        float sn, cs;
        sincosf((float)p, &sn, &cs);
        float a = m * cs, bb = m * sn;
        u16* pr = dst + (size_t)row * K3IR_;
        u16 ha = f2bf(a), la = f2bf(a - bf2f(ha));
        pr[ccol] = ha; pr[KE_ + ccol] = la; pr[2 * KE_ + ccol] = ha;
        u16 hb = f2bf(bb), lb = f2bf(bb - bf2f(hb));
        pr[scol] = hb; pr[KE_ + scol] = lb; pr[2 * KE_ + scol] = hb;
    }
}

// ---------------- zero the pad columns of AB3e/AB3o (content: even 258, odd 256) ------
__global__ void zeropad_kernel(u16* __restrict__ ABe, u16* __restrict__ ABo) {
    int row = blockIdx.x;
    int t = threadIdx.x;   // 256
    u16* re = ABe + (size_t)row * K3IR_;
    u16* ro = ABo + (size_t)row * K3IR_;
    if (t < 122) {
        int col = (t < 90) ? ((t / 30) * KE_ + 258 + (t % 30)) : (864 + (t - 90));
        re[col] = 0;
    } else if (t < 250) {
        int u = t - 122;
        int col = (u < 96) ? ((u / 32) * KE_ + 256 + (u % 32)) : (864 + (u - 96));
        ro[col] = 0;
    }
}

// ---------------- parity irfft tables, triplet [z][n=256][896] (hi|hi|lo) -------------
__global__ void table3_kernel(u16* __restrict__ Tt3) {
    int idx = blockIdx.x * 256 + threadIdx.x;
    if (idx >= 2 * 256 * KE_) return;
    int z = idx / (256 * KE_);
    int r = idx - z * (256 * KE_);
    int n = r / KE_, j = r - n * KE_;
    float val = 0.f;
    if (z == 0) {
        if (j < 129) {
            int k = 2 * j;
            float w = (k == 0 || k == 256) ? 1.f : 2.f;
            int m = (k * n) & 511;
            val = w * (1.f / 512.f) * cosf((float)m * (PI_ / 256.f));
        } else if (j < 258) {
            int kk = 2 * (j - 129);
            float w = (kk == 0 || kk == 256) ? 1.f : 2.f;
            int m = (kk * n) & 511;
            val = -w * (1.f / 512.f) * sinf((float)m * (PI_ / 256.f));
        }
    } else {
        if (j < 128) {
            int k = 2 * j + 1;
            int m = (k * n) & 511;
            val = 2.f * (1.f / 512.f) * cosf((float)m * (PI_ / 256.f));
        } else if (j < 256) {
            int kk = 2 * (j - 128) + 1;
            int m = (kk * n) & 511;
            val = -2.f * (1.f / 512.f) * sinf((float)m * (PI_ / 256.f));
        }
    }
    u16 h = f2bf(val), lo = f2bf(val - bf2f(h));
    u16* p = Tt3 + (size_t)z * 256 * K3IR_ + (size_t)n * K3IR_ + j;
    p[0] = h; p[KE_] = h; p[2 * KE_] = lo;
}

// (pad writer for table cols 864..895)
__global__ void tablepad_kernel(u16* __restrict__ Tt3) {
    int idx = blockIdx.x * 256 + threadIdx.x;   // 2*256*32
    if (idx >= 2 * 256 * 32) return;
    int z = idx / (256 * 32);
    int r = idx - z * (256 * 32);
    int n = r >> 5, j = r & 31;
    Tt3[(size_t)z * 256 * K3IR_ + (size_t)n * K3IR_ + 864 + j] = 0;
}

// ---------------- overlap-add with hann + parity combine ----------------
__global__ void ola2_kernel(const float* __restrict__ E, const float* __restrict__ O,
                            float* __restrict__ sig) {
    int idx = blockIdx.x * 256 + threadIdx.x;   // 32*32768
    int b = idx >> 15;
    int t = idx & (NS_ - 1);
    int q = t >> 8, r = t & 255;
    float c = cosf((float)r * (PI_ / 256.f));
    float hr  = 0.5f - 0.5f * c;
    float hr2 = 0.5f + 0.5f * c;
    size_t row = (size_t)(b * NF_ + q) * 256 + r;
    float v = hr * (E[row] + O[row]);
    if (q > 0) v += hr2 * (E[row - 256] - O[row - 256]);
    sig[idx] = v;
}

// ---------------- tap compaction ----------------
__global__ void compact_kernel(const float* __restrict__ times, int* __restrict__ cnt,
                               float2* __restrict__ taps) {
    int be = blockIdx.x;
    int k = threadIdx.x;
    __shared__ int c;
    if (k == 0) c = 0;
    __syncthreads();
    float v = times[(size_t)be * NF_ + k];
    if (v != 0.f) {
        int slot = atomicAdd(&c, 1);
        taps[(size_t)be * NF_ + slot] = make_float2((float)k, v);
    }
    __syncthreads();
    if (k == 0) cnt[be] = c;
}

// ---------------- sparse conv (compact taps) ----------------
__global__ __launch_bounds__(256) void conv_kernel(const float* __restrict__ sig,
                                                   const int* __restrict__ cnt,
                                                   const float2* __restrict__ taps,
                                                   float* __restrict__ out) {
    int be = blockIdx.y;
    int b = be >> 4;
    int n = cnt[be];
    int t = blockIdx.x * 2048 + (int)threadIdx.x * 8;
    const float* sg = sig + (size_t)b * NS_;
    float4 a0 = make_float4(0.f, 0.f, 0.f, 0.f);
    float4 a1 = make_float4(0.f, 0.f, 0.f, 0.f);
    for (int i = 0; i < n; ++i) {
        float2 ka = taps[(size_t)be * NF_ + i];
        int s = t - ((int)ka.x << 8);
        float amp = ka.y;
        if (s >= 0) {
            float4 v0 = *(const float4*)(sg + s);
            float4 v1 = *(const float4*)(sg + s + 4);
            a0.x += amp * v0.x; a0.y += amp * v0.y; a0.z += amp * v0.z; a0.w += amp * v0.w;
            a1.x += amp * v1.x; a1.y += amp * v1.y; a1.z += amp * v1.z; a1.w += amp * v1.w;
        }
    }
    float* op = out + (size_t)be * NS_ + t;
    *(float4*)op = a0;
    *(float4*)(op + 4) = a1;
}

extern "C" void kernel_launch(void* const* d_in, const int* in_sizes, int n_in,
                              void* d_out, int out_size, void* d_ws, size_t ws_size,
                              hipStream_t stream) {
    const float* param  = (const float*)d_in[0];
    const float* times  = (const float*)d_in[1];
    const float* noise  = (const float*)d_in[2];
    const float* pos    = (const float*)d_in[3];
    const float* proj_w = (const float*)d_in[4];
    const float* proj_b = (const float*)d_in[5];
    const float* w0 = (const float*)d_in[6];
    const float* b0 = (const float*)d_in[7];
    const float* w1 = (const float*)d_in[8];
    const float* b1 = (const float*)d_in[9];
    const float* w2 = (const float*)d_in[10];
    const float* b2 = (const float*)d_in[11];
    const float* w_out = (const float*)d_in[12];
    const float* b_out = (const float*)d_in[13];
    float* out = (float*)d_out;
    float* ws = (float*)d_ws;

    // ws layout — cursor in FLOAT units; u16 buffers consume (u16_count/2) floats.
    // (R5 failure root-cause: these were divided by 4, overlapping H buffers.)
    constexpr size_t S_F    = 192 * 256;                   //      49,152
    constexpr size_t YP_F   = 192 * 256;                   //      49,152
    constexpr size_t H3_F   = (size_t)ROWS_ * K3MLP_ / 2;  //   1,572,864 per buffer
    constexpr size_t W3_F   = (size_t)256 * K3MLP_ / 2;    //      98,304
    constexpr size_t WO3_F  = (size_t)576 * K3MLP_ / 2;    //     221,184
    constexpr size_t RAW_F  = (size_t)ROWS_ * TC_;         //   2,105,344
    constexpr size_t AB3_F  = 2 * (size_t)ROWS_ * K3IR_ / 2; // 3,670,016
    constexpr size_t TT3_F  = 2 * (size_t)256 * K3IR_ / 2; //     229,376
    constexpr size_t EO_F   = 2 * (size_t)ROWS_ * 256;     //   2,097,152
    constexpr size_t SIG_F  = (size_t)B_ * NS_;            //   1,048,576
    constexpr size_t SUMS_F = (size_t)B_ * NCH_ * NC_ * 2; //     263,168

    size_t cur = 0;
    float* S    = ws + cur;                 cur += S_F;
    float* YP   = ws + cur;                 cur += YP_F;
    u16*  H1_3  = (u16*)(ws + cur);         cur += H3_F;
    u16*  H2_3  = (u16*)(ws + cur);         cur += H3_F;
    u16*  H3_3  = (u16*)(ws + cur);         cur += H3_F;
    u16*  W1_3  = (u16*)(ws + cur);         cur += W3_F;
    u16*  W2_3  = (u16*)(ws + cur);         cur += W3_F;
    u16*  WO_3  = (u16*)(ws + cur);         cur += WO3_F;
    float* RAW  = ws + cur;                 cur += RAW_F;
    u16*  AB3   = (u16*)(ws + cur);         cur += AB3_F;
    u16*  AB3e  = AB3;
    u16*  AB3o  = AB3 + (size_t)ROWS_ * K3IR_;
    u16*  Tt3   = (u16*)(ws + cur);         cur += TT3_F;
    float* EO   = ws + cur;                 cur += EO_F;
    float* SIG  = ws + cur;                 cur += SIG_F;
    double* SUMS = (double*)(ws + cur);     cur += SUMS_F;
    int*   CNT  = (int*)(ws + cur);         cur += 512;
    float2* TAPS = (float2*)(ws + cur);     // 512*128 float2

    // independent prep
    table3_kernel<<<(2 * 256 * KE_ + 255) / 256, 256, 0, stream>>>(Tt3);
    tablepad_kernel<<<(2 * 256 * 32 + 255) / 256, 256, 0, stream>>>(Tt3);
    compact_kernel<<<B_ * NE_, NF_, 0, stream>>>(times, CNT, TAPS);
    wconv_kernel<<<(256 * 256 + 255) / 256, 256, 0, stream>>>(w1, W1_3, 256, 256);
    wconv_kernel<<<(256 * 256 + 255) / 256, 256, 0, stream>>>(w2, W2_3, 256, 256);
    wconv_kernel<<<(576 * 256 + 255) / 256, 256, 0, stream>>>(w_out, WO_3, 514, 576);
    // layer-1 collapse (fp32): YP = S @ w0^T (192x256x256)
    proj_kernel<<<B_, CH_, 0, stream>>>(param, proj_w, proj_b, S);
    stackpos_kernel<<<160, 256, 0, stream>>>(pos, S);
    gemm2<<<dim3(4, 3, 1), 256, 0, stream>>>(S, w0, YP, 192, CH_, CH_, CH_, CH_, CH_);
    fuse1_kernel<<<ROWS_ * CH_ / 256, 256, 0, stream>>>(YP, b0, H1_3);
    // MLP layers 2,3 (bf16-split MFMA, triplet out)
    mfgemm<0><<<dim3(4, 64, 1), 256, 0, stream>>>(H1_3, W1_3, b1, H2_3, 256, K3MLP_,
                                                  K3MLP_, K3MLP_, K3MLP_, 0, 0, 0);
    mfgemm<0><<<dim3(4, 64, 1), 256, 0, stream>>>(H2_3, W2_3, b2, H3_3, 256, K3MLP_,
                                                  K3MLP_, K3MLP_, K3MLP_, 0, 0, 0);
    // output layer -> RAW fp32 (bias, N=514 guarded)
    mfgemm<1><<<dim3(9, 64, 1), 256, 0, stream>>>(H3_3, WO_3, b_out, RAW, TC_, K3MLP_,
                                                  K3MLP_, K3MLP_, TC_, 0, 0, 0);
    // phase scan (double carry) -> AB3 triplets; pads zeroed
    dim3 gS(B_, NCH_);
    scan1_kernel<<<gS, 320, 0, stream>>>(RAW, noise, SUMS);
    zeropad_kernel<<<ROWS_, 256, 0, stream>>>(AB3e, AB3o);
    scan2_kernel<<<gS, 320, 0, stream>>>(RAW, noise, SUMS, AB3e, AB3o);
    // parity irfft (z-batched): EO[z] = AB3[z] @ Tt3[z]^T
    mfgemm<2><<<dim3(4, 64, 2), 256, 0, stream>>>(AB3, Tt3, nullptr, EO, 256, K3IR_,
                                                  K3IR_, K3IR_, 256,
                                                  (size_t)ROWS_ * K3IR_, (size_t)256 * K3IR_,
                                                  (size_t)ROWS_ * 256);
    // overlap-add + hann + parity combine -> SIG
    ola2_kernel<<<B_ * NS_ / 256, 256, 0, stream>>>(EO, EO + (size_t)ROWS_ * 256, SIG);
    // sparse conv -> out
    dim3 gC(NS_ / 2048, B_ * NE_);
    conv_kernel<<<gC, 256, 0, stream>>>(SIG, CNT, TAPS, out);
}

// Round 7
// 117.832 us; speedup vs baseline: 2.2379x; 1.1094x over previous
//
#include <hip/hip_runtime.h>
#include <cstddef>

typedef unsigned short u16;
typedef __bf16 bf16x8 __attribute__((ext_vector_type(8)));
typedef float f32x4 __attribute__((ext_vector_type(4)));

// Problem constants
constexpr int B_   = 32;
constexpr int CTX_ = 128;
constexpr int NF_  = 128;     // frames
constexpr int NS_  = 32768;   // samples
constexpr int NE_  = 16;      // events
constexpr int CH_  = 256;
constexpr int NC_  = 257;     // coeffs
constexpr int TC_  = 514;     // 2*coeffs
constexpr int ROWS_ = B_ * NF_;  // 4096
constexpr int CHUNK_ = 8;        // frames per scan chunk
constexpr int NCH_ = NF_ / CHUNK_;  // 16 chunks
constexpr int KE_ = 288;         // parity-K for irfft (content 258/256, padded)
constexpr int K3MLP_ = 768;      // 3*256
constexpr int K3IR_ = 896;       // 3*288=864, padded to 64-mult
constexpr float PI_ = 3.14159265358979323846f;

__device__ __forceinline__ float lrelu(float v) { return v > 0.f ? v : 0.2f * v; }
__device__ __forceinline__ u16 f2bf(float x) {
    unsigned u = __float_as_uint(x);
    return (u16)((u + 0x7FFFu + ((u >> 16) & 1u)) >> 16);
}
__device__ __forceinline__ float bf2f(u16 h) { return __uint_as_float(((unsigned)h) << 16); }

// ---------------- projstack: S rows 0..31 proj, 32..159 pos, 160..191 zero ----------
__global__ void projstack_kernel(const float* __restrict__ param, const float* __restrict__ pw,
                                 const float* __restrict__ pb, const float* __restrict__ pos,
                                 float* __restrict__ S) {
    int b = blockIdx.x;      // 192
    int c = threadIdx.x;     // 256
    float v;
    if (b < 32) {
        const float* pr = param + b * CTX_;
        const float* wr = pw + c * CTX_;
        float s = 0.f;
        #pragma unroll 4
        for (int j = 0; j < CTX_; ++j) s += pr[j] * wr[j];
        v = s + pb[c];
    } else if (b < 160) {
        v = pos[(b - 32) * CH_ + c];
    } else {
        v = 0.f;
    }
    S[b * CH_ + c] = v;
}

// ---------------- fp32 gemm (layer-1 only): C = A @ B^T, 64x64 tile, BK=32 ----------
__global__ __launch_bounds__(256) void gemm2(
    const float* __restrict__ A, const float* __restrict__ Bm, float* __restrict__ C,
    int M, int N, int K, int lda, int ldb, int ldc)
{
    const int tid = threadIdx.x;
    const int tx = tid & 15, ty = tid >> 4;
    const int m0 = blockIdx.y * 64, n0 = blockIdx.x * 64;
    __shared__ __align__(16) float As[32][64];
    __shared__ __align__(16) float Bs[32][64];
    const int ar = tid & 63, akg = (tid >> 6) * 8;
    float4 ra0, ra1, rb0, rb1;
    auto loadA = [&](int kt) {
        const float* p = A + (size_t)(m0 + ar) * lda + kt + akg;
        ra0 = *(const float4*)p; ra1 = *(const float4*)(p + 4);
    };
    auto loadB = [&](int kt) {
        const float* p = Bm + (size_t)(n0 + ar) * ldb + kt + akg;
        rb0 = *(const float4*)p; rb1 = *(const float4*)(p + 4);
    };
    loadA(0); loadB(0);
    float acc[4][4] = {};
    for (int kt = 0; kt < K; kt += 32) {
        As[akg+0][ar] = ra0.x; As[akg+1][ar] = ra0.y; As[akg+2][ar] = ra0.z; As[akg+3][ar] = ra0.w;
        As[akg+4][ar] = ra1.x; As[akg+5][ar] = ra1.y; As[akg+6][ar] = ra1.z; As[akg+7][ar] = ra1.w;
        Bs[akg+0][ar] = rb0.x; Bs[akg+1][ar] = rb0.y; Bs[akg+2][ar] = rb0.z; Bs[akg+3][ar] = rb0.w;
        Bs[akg+4][ar] = rb1.x; Bs[akg+5][ar] = rb1.y; Bs[akg+6][ar] = rb1.z; Bs[akg+7][ar] = rb1.w;
        __syncthreads();
        if (kt + 32 < K) { loadA(kt + 32); loadB(kt + 32); }
        #pragma unroll
        for (int kk = 0; kk < 32; ++kk) {
            float4 av = *(const float4*)&As[kk][ty*4];
            float4 bv = *(const float4*)&Bs[kk][tx*4];
            float a4[4] = {av.x, av.y, av.z, av.w};
            float b4[4] = {bv.x, bv.y, bv.z, bv.w};
            #pragma unroll
            for (int i = 0; i < 4; ++i)
                #pragma unroll
                for (int j = 0; j < 4; ++j)
                    acc[i][j] += a4[i] * b4[j];
        }
        __syncthreads();
    }
    #pragma unroll
    for (int i = 0; i < 4; ++i)
        #pragma unroll
        for (int j = 0; j < 4; ++j)
            C[(size_t)(m0 + ty*4 + i) * ldc + n0 + tx*4 + j] = acc[i][j];
}

// ---------------- fuse1: H1_3 triplet = lrelu(YP[b] + YP[32+f] + b0) ----------------
__global__ void fuse1_kernel(const float* __restrict__ YP, const float* __restrict__ b0,
                             u16* __restrict__ H3) {
    int idx = blockIdx.x * 256 + threadIdx.x;   // 4096*256
    int c = idx & 255;
    int row = idx >> 8;
    int b = row >> 7, f = row & 127;
    float v = lrelu(YP[b * CH_ + c] + YP[(32 + f) * CH_ + c] + b0[c]);
    u16 h = f2bf(v), lo = f2bf(v - bf2f(h));
    u16* p = H3 + (size_t)row * K3MLP_;
    p[c] = h; p[256 + c] = lo; p[512 + c] = h;
}

// ---------------- unified weight conversion: w1|w2|w_out -> triplets (hi|hi|lo) -------
__global__ void wconvu_kernel(const float* __restrict__ w1, const float* __restrict__ w2,
                              const float* __restrict__ wo,
                              u16* __restrict__ W1_3, u16* __restrict__ W2_3,
                              u16* __restrict__ WO_3) {
    int row = blockIdx.x;        // 0..1087
    int k = threadIdx.x;         // 256
    float v;
    u16* p;
    if (row < 256) {
        v = w1[row * 256 + k];
        p = W1_3 + (size_t)row * K3MLP_;
    } else if (row < 512) {
        v = w2[(row - 256) * 256 + k];
        p = W2_3 + (size_t)(row - 256) * K3MLP_;
    } else {
        int n = row - 512;       // 0..575, valid < 514
        v = (n < TC_) ? wo[n * 256 + k] : 0.f;
        p = WO_3 + (size_t)n * K3MLP_;
    }
    u16 h = f2bf(v), lo = f2bf(v - bf2f(h));
    p[k] = h; p[256 + k] = h; p[512 + k] = lo;
}

// ---------------- mfgemm: C = A3 @ B3^T, bf16-split MFMA, 64x64 tile, BK=64 ----------
// Double-buffered LDS, one barrier per K-step, prefetch next K-step during MFMA.
// EPI 0: bias+lrelu -> bf16 triplet (ldc=768, hi|lo|hi at n, 256+n, 512+n)
// EPI 1: bias -> fp32 (N-guarded)
// EPI 2: plain fp32 (z-batched C)
template<int EPI>
__global__ __launch_bounds__(256) void mfgemm(
    const u16* __restrict__ A3, const u16* __restrict__ B3,
    const float* __restrict__ bias, void* __restrict__ Cout,
    int N, int K3, int lda, int ldb, int ldc,
    size_t sAz, size_t sBz, size_t sCz)
{
    A3 += (size_t)blockIdx.z * sAz;
    B3 += (size_t)blockIdx.z * sBz;
    const int tid = threadIdx.x;
    const int m0 = blockIdx.y * 64, n0 = blockIdx.x * 64;
    __shared__ __align__(16) u16 Als[2 * 64 * 64];
    __shared__ __align__(16) u16 Bls[2 * 64 * 64];
    // staging: thread -> row (tid>>2), 32B chunk ((tid&3)*32B), XOR-swizzled LDS store
    const int sr = tid >> 2;
    const int sc = (tid & 3) * 16;                 // ushort offset
    const u16* ga = A3 + (size_t)(m0 + sr) * lda + sc;
    const u16* gb = B3 + (size_t)(n0 + sr) * ldb + sc;
    const int xr = (sr & 7) << 4;
    const int lo0 = sr * 128 + ((sc * 2) ^ xr);        // byte offset within buffer
    const int lo1 = sr * 128 + ((sc * 2 + 16) ^ xr);
    // fragment maps: 4 waves, each 32x32 (2x2 frags of 16x16)
    const int wv = tid >> 6, lane = tid & 63;
    const int wr = (wv >> 1) * 32, wc = (wv & 1) * 32;
    const int lr = lane & 15;
    const int lkb = (lane >> 4) * 16;              // byte offset of 8-bf16 group
    const int xf = (lr & 7) << 4;
    const int ra0 = (wr + lr) * 128, ra1 = (wr + 16 + lr) * 128;
    const int rb0 = (wc + lr) * 128, rb1 = (wc + 16 + lr) * 128;
    f32x4 acc00 = {0.f, 0.f, 0.f, 0.f}, acc01 = acc00, acc10 = acc00, acc11 = acc00;
    uint4 va0 = *(const uint4*)(ga);
    uint4 va1 = *(const uint4*)(ga + 8);
    uint4 vb0 = *(const uint4*)(gb);
    uint4 vb1 = *(const uint4*)(gb + 8);
    int p = 0;
    for (int kt = 0; kt < K3; kt += 64) {
        char* ab = (char*)Als + p * 8192;
        char* bb = (char*)Bls + p * 8192;
        *(uint4*)(ab + lo0) = va0; *(uint4*)(ab + lo1) = va1;
        *(uint4*)(bb + lo0) = vb0; *(uint4*)(bb + lo1) = vb1;
        __syncthreads();
        if (kt + 64 < K3) {
            va0 = *(const uint4*)(ga + kt + 64);
            va1 = *(const uint4*)(ga + kt + 64 + 8);
            vb0 = *(const uint4*)(gb + kt + 64);
            vb1 = *(const uint4*)(gb + kt + 64 + 8);
        }
        const char* pa = (const char*)Als + p * 8192;
        const char* pb = (const char*)Bls + p * 8192;
        #pragma unroll
        for (int s = 0; s < 2; ++s) {
            int kb = (s * 64 + lkb) ^ xf;
            bf16x8 a0 = *(const bf16x8*)(pa + ra0 + kb);
            bf16x8 a1 = *(const bf16x8*)(pa + ra1 + kb);
            bf16x8 b0 = *(const bf16x8*)(pb + rb0 + kb);
            bf16x8 b1 = *(const bf16x8*)(pb + rb1 + kb);
            acc00 = __builtin_amdgcn_mfma_f32_16x16x32_bf16(a0, b0, acc00, 0, 0, 0);
            acc01 = __builtin_amdgcn_mfma_f32_16x16x32_bf16(a0, b1, acc01, 0, 0, 0);
            acc10 = __builtin_amdgcn_mfma_f32_16x16x32_bf16(a1, b0, acc10, 0, 0, 0);
            acc11 = __builtin_amdgcn_mfma_f32_16x16x32_bf16(a1, b1, acc11, 0, 0, 0);
        }
        p ^= 1;
    }
    // epilogue: D[row=(lane>>4)*4+r][col=lane&15] per frag
    const int er = (lane >> 4) * 4;
    const int ec = lane & 15;
    auto emit = [&](const f32x4& A, int mi, int ni) {
        #pragma unroll
        for (int r = 0; r < 4; ++r) {
            int m = m0 + wr + mi * 16 + er + r;
            int n = n0 + wc + ni * 16 + ec;
            float v = A[r];
            if (EPI == 0) {
                v = lrelu(v + bias[n]);
                u16 h = f2bf(v), lo = f2bf(v - bf2f(h));
                u16* p2 = (u16*)Cout + (size_t)m * ldc + n;
                p2[0] = h; p2[256] = lo; p2[512] = h;
            } else if (EPI == 1) {
                if (n < N) ((float*)Cout)[(size_t)m * ldc + n] = v + bias[n];
            } else {
                float* cf = (float*)Cout + (size_t)blockIdx.z * sCz;
                cf[(size_t)m * ldc + n] = v;
            }
        }
    };
    emit(acc00, 0, 0); emit(acc01, 0, 1); emit(acc10, 1, 0); emit(acc11, 1, 1);
}

// ---------------- scan pass 1: per-chunk sum of dphi (double) ----------------
__global__ void scan1_kernel(const float* __restrict__ raw, const float* __restrict__ noise,
                             double* __restrict__ sums) {
    int b = blockIdx.x, c = blockIdx.y;
    int k = threadIdx.x;
    if (k >= NC_) return;
    float kf = (float)k * (PI_ / 256.f);
    double s = 0.0;
    #pragma unroll
    for (int j = 0; j < CHUNK_; ++j) {
        int row = b * NF_ + c * CHUNK_ + j;
        float2 v = *(const float2*)(raw + (size_t)row * TC_ + 2 * k);
        float d = (1.f + v.y * noise[(size_t)row * NC_ + k]) * kf;
        s += (double)d;
    }
    sums[((size_t)(b * NCH_ + c)) * NC_ + k] = s;
}

// ---------------- scan pass 2: prefix + sincos -> parity triplets; pads inline --------
__global__ void scan2_kernel(const float* __restrict__ raw, const float* __restrict__ noise,
                             const double* __restrict__ sums,
                             u16* __restrict__ AB3e, u16* __restrict__ AB3o) {
    int b = blockIdx.x, c = blockIdx.y;
    int k = threadIdx.x;
    if (k >= NC_) {
        // threads 257..319 zero pad columns for this (b, chunk)'s 8 rows
        int t = k - NC_;   // 0..62
        for (int idx = t; idx < 250; idx += 63) {
            int col;
            u16* base;
            if (idx < 122) {
                col = (idx < 90) ? ((idx / 30) * KE_ + 258 + (idx % 30)) : (864 + (idx - 90));
                base = AB3e;
            } else {
                int u = idx - 122;
                col = (u < 96) ? ((u / 32) * KE_ + 256 + (u % 32)) : (864 + (u - 96));
                base = AB3o;
            }
            for (int j = 0; j < CHUNK_; ++j)
                base[(size_t)(b * NF_ + c * CHUNK_ + j) * K3IR_ + col] = 0;
        }
        return;
    }
    double p = 0.0;
    for (int cc = 0; cc < c; ++cc)
        p += sums[((size_t)(b * NCH_ + cc)) * NC_ + k];
    float kf = (float)k * (PI_ / 256.f);
    int half = k >> 1;
    bool even = (k & 1) == 0;
    int ccol = half;
    int scol = even ? (129 + half) : (128 + half);
    u16* dst = even ? AB3e : AB3o;
    for (int j = 0; j < CHUNK_; ++j) {
        int row = b * NF_ + c * CHUNK_ + j;
        float2 v = *(const float2*)(raw + (size_t)row * TC_ + 2 * k);
        float d = (1.f + v.y * noise[(size_t)row * NC_ + k]) * kf;
        p += (double)d;
        float m = fabsf(v.x);
        float sn, cs;
        sincosf((float)p, &sn, &cs);
        float a = m * cs, bb = m * sn;
        u16* pr = dst + (size_t)row * K3IR_;
        u16 ha = f2bf(a), la = f2bf(a - bf2f(ha));
        pr[ccol] = ha; pr[KE_ + ccol] = la; pr[2 * KE_ + ccol] = ha;
        u16 hb = f2bf(bb), lb = f2bf(bb - bf2f(hb));
        pr[scol] = hb; pr[KE_ + scol] = lb; pr[2 * KE_ + scol] = hb;
    }
}

// ---------------- parity irfft tables, per-element incl. pads ------------------------
// Tt3[z][n][col]: col<864: seg=col/288, j=col%288, val=f(z,n,j); seg<2 -> hi, seg 2 -> lo.
// col>=864 -> 0.
__global__ void table3_kernel(u16* __restrict__ Tt3) {
    int idx = blockIdx.x * 256 + threadIdx.x;
    if (idx >= 2 * 256 * K3IR_) return;
    int z = idx / (256 * K3IR_);
    int r = idx - z * (256 * K3IR_);
    int n = r / K3IR_, col = r - n * K3IR_;
    u16 outv = 0;
    if (col < 864) {
        int seg = col / KE_;
        int j = col - seg * KE_;
        float val = 0.f;
        if (z == 0) {
            if (j < 129) {
                int k = 2 * j;
                float w = (k == 0 || k == 256) ? 1.f : 2.f;
                int m = (k * n) & 511;
                val = w * (1.f / 512.f) * cosf((float)m * (PI_ / 256.f));
            } else if (j < 258) {
                int kk = 2 * (j - 129);
                float w = (kk == 0 || kk == 256) ? 1.f : 2.f;
                int m = (kk * n) & 511;
                val = -w * (1.f / 512.f) * sinf((float)m * (PI_ / 256.f));
            }
        } else {
            if (j < 128) {
                int k = 2 * j + 1;
                int m = (k * n) & 511;
                val = 2.f * (1.f / 512.f) * cosf((float)m * (PI_ / 256.f));
            } else if (j < 256) {
                int kk = 2 * (j - 128) + 1;
                int m = (kk * n) & 511;
                val = -2.f * (1.f / 512.f) * sinf((float)m * (PI_ / 256.f));
            }
        }
        u16 h = f2bf(val);
        outv = (seg < 2) ? h : f2bf(val - bf2f(h));
    }
    Tt3[idx] = outv;
}

// ---------------- overlap-add with hann + parity combine ----------------
__global__ void ola2_kernel(const float* __restrict__ E, const float* __restrict__ O,
                            float* __restrict__ sig) {
    int idx = blockIdx.x * 256 + threadIdx.x;   // 32*32768
    int b = idx >> 15;
    int t = idx & (NS_ - 1);
    int q = t >> 8, r = t & 255;
    float c = cosf((float)r * (PI_ / 256.f));
    float hr  = 0.5f - 0.5f * c;
    float hr2 = 0.5f + 0.5f * c;
    size_t row = (size_t)(b * NF_ + q) * 256 + r;
    float v = hr * (E[row] + O[row]);
    if (q > 0) v += hr2 * (E[row - 256] - O[row - 256]);
    sig[idx] = v;
}

// ---------------- tap compaction ----------------
__global__ void compact_kernel(const float* __restrict__ times, int* __restrict__ cnt,
                               float2* __restrict__ taps) {
    int be = blockIdx.x;
    int k = threadIdx.x;
    __shared__ int c;
    if (k == 0) c = 0;
    __syncthreads();
    float v = times[(size_t)be * NF_ + k];
    if (v != 0.f) {
        int slot = atomicAdd(&c, 1);
        taps[(size_t)be * NF_ + slot] = make_float2((float)k, v);
    }
    __syncthreads();
    if (k == 0) cnt[be] = c;
}

// ---------------- sparse conv (compact taps) ----------------
__global__ __launch_bounds__(256) void conv_kernel(const float* __restrict__ sig,
                                                   const int* __restrict__ cnt,
                                                   const float2* __restrict__ taps,
                                                   float* __restrict__ out) {
    int be = blockIdx.y;
    int b = be >> 4;
    int n = cnt[be];
    int t = blockIdx.x * 2048 + (int)threadIdx.x * 8;
    const float* sg = sig + (size_t)b * NS_;
    float4 a0 = make_float4(0.f, 0.f, 0.f, 0.f);
    float4 a1 = make_float4(0.f, 0.f, 0.f, 0.f);
    for (int i = 0; i < n; ++i) {
        float2 ka = taps[(size_t)be * NF_ + i];
        int s = t - ((int)ka.x << 8);
        float amp = ka.y;
        if (s >= 0) {
            float4 v0 = *(const float4*)(sg + s);
            float4 v1 = *(const float4*)(sg + s + 4);
            a0.x += amp * v0.x; a0.y += amp * v0.y; a0.z += amp * v0.z; a0.w += amp * v0.w;
            a1.x += amp * v1.x; a1.y += amp * v1.y; a1.z += amp * v1.z; a1.w += amp * v1.w;
        }
    }
    float* op = out + (size_t)be * NS_ + t;
    *(float4*)op = a0;
    *(float4*)(op + 4) = a1;
}

extern "C" void kernel_launch(void* const* d_in, const int* in_sizes, int n_in,
                              void* d_out, int out_size, void* d_ws, size_t ws_size,
                              hipStream_t stream) {
    const float* param  = (const float*)d_in[0];
    const float* times  = (const float*)d_in[1];
    const float* noise  = (const float*)d_in[2];
    const float* pos    = (const float*)d_in[3];
    const float* proj_w = (const float*)d_in[4];
    const float* proj_b = (const float*)d_in[5];
    const float* w0 = (const float*)d_in[6];
    const float* b0 = (const float*)d_in[7];
    const float* w1 = (const float*)d_in[8];
    const float* b1 = (const float*)d_in[9];
    const float* w2 = (const float*)d_in[10];
    const float* b2 = (const float*)d_in[11];
    const float* w_out = (const float*)d_in[12];
    const float* b_out = (const float*)d_in[13];
    float* out = (float*)d_out;
    float* ws = (float*)d_ws;

    // ws layout — cursor in FLOAT units; u16 buffers consume (u16_count/2) floats.
    constexpr size_t S_F    = 192 * 256;                   //      49,152
    constexpr size_t YP_F   = 192 * 256;                   //      49,152
    constexpr size_t H3_F   = (size_t)ROWS_ * K3MLP_ / 2;  //   1,572,864 per buffer
    constexpr size_t W3_F   = (size_t)256 * K3MLP_ / 2;    //      98,304
    constexpr size_t WO3_F  = (size_t)576 * K3MLP_ / 2;    //     221,184
    constexpr size_t RAW_F  = (size_t)ROWS_ * TC_;         //   2,105,344
    constexpr size_t AB3_F  = 2 * (size_t)ROWS_ * K3IR_ / 2; // 3,670,016
    constexpr size_t TT3_F  = 2 * (size_t)256 * K3IR_ / 2; //     229,376
    constexpr size_t EO_F   = 2 * (size_t)ROWS_ * 256;     //   2,097,152
    constexpr size_t SIG_F  = (size_t)B_ * NS_;            //   1,048,576
    constexpr size_t SUMS_F = (size_t)B_ * NCH_ * NC_ * 2; //     263,168

    size_t cur = 0;
    float* S    = ws + cur;                 cur += S_F;
    float* YP   = ws + cur;                 cur += YP_F;
    u16*  H1_3  = (u16*)(ws + cur);         cur += H3_F;
    u16*  H2_3  = (u16*)(ws + cur);         cur += H3_F;
    u16*  H3_3  = (u16*)(ws + cur);         cur += H3_F;
    u16*  W1_3  = (u16*)(ws + cur);         cur += W3_F;
    u16*  W2_3  = (u16*)(ws + cur);         cur += W3_F;
    u16*  WO_3  = (u16*)(ws + cur);         cur += WO3_F;
    float* RAW  = ws + cur;                 cur += RAW_F;
    u16*  AB3   = (u16*)(ws + cur);         cur += AB3_F;
    u16*  AB3e  = AB3;
    u16*  AB3o  = AB3 + (size_t)ROWS_ * K3IR_;
    u16*  Tt3   = (u16*)(ws + cur);         cur += TT3_F;
    float* EO   = ws + cur;                 cur += EO_F;
    float* SIG  = ws + cur;                 cur += SIG_F;
    double* SUMS = (double*)(ws + cur);     cur += SUMS_F;
    int*   CNT  = (int*)(ws + cur);         cur += 512;
    float2* TAPS = (float2*)(ws + cur);     // 512*128 float2

    // independent prep (3 kernels)
    table3_kernel<<<(2 * 256 * K3IR_ + 255) / 256, 256, 0, stream>>>(Tt3);
    compact_kernel<<<B_ * NE_, NF_, 0, stream>>>(times, CNT, TAPS);
    wconvu_kernel<<<1088, 256, 0, stream>>>(w1, w2, w_out, W1_3, W2_3, WO_3);
    // layer-1 collapse (fp32): YP = S @ w0^T (192x256x256)
    projstack_kernel<<<192, 256, 0, stream>>>(param, proj_w, proj_b, pos, S);
    gemm2<<<dim3(4, 3, 1), 256, 0, stream>>>(S, w0, YP, 192, CH_, CH_, CH_, CH_, CH_);
    fuse1_kernel<<<ROWS_ * CH_ / 256, 256, 0, stream>>>(YP, b0, H1_3);
    // MLP layers 2,3 (bf16-split MFMA, triplet out)
    mfgemm<0><<<dim3(4, 64, 1), 256, 0, stream>>>(H1_3, W1_3, b1, H2_3, 256, K3MLP_,
                                                  K3MLP_, K3MLP_, K3MLP_, 0, 0, 0);
    mfgemm<0><<<dim3(4, 64, 1), 256, 0, stream>>>(H2_3, W2_3, b2, H3_3, 256, K3MLP_,
                                                  K3MLP_, K3MLP_, K3MLP_, 0, 0, 0);
    // output layer -> RAW fp32 (bias, N=514 guarded)
    mfgemm<1><<<dim3(9, 64, 1), 256, 0, stream>>>(H3_3, WO_3, b_out, RAW, TC_, K3MLP_,
                                                  K3MLP_, K3MLP_, TC_, 0, 0, 0);
    // phase scan (double carry) -> AB3 triplets (pads written by spare threads)
    dim3 gS(B_, NCH_);
    scan1_kernel<<<gS, 320, 0, stream>>>(RAW, noise, SUMS);
    scan2_kernel<<<gS, 320, 0, stream>>>(RAW, noise, SUMS, AB3e, AB3o);
    // parity irfft (z-batched): EO[z] = AB3[z] @ Tt3[z]^T
    mfgemm<2><<<dim3(4, 64, 2), 256, 0, stream>>>(AB3, Tt3, nullptr, EO, 256, K3IR_,
                                                  K3IR_, K3IR_, 256,
                                                  (size_t)ROWS_ * K3IR_, (size_t)256 * K3IR_,
                                                  (size_t)ROWS_ * 256);
    // overlap-add + hann + parity combine -> SIG
    ola2_kernel<<<B_ * NS_ / 256, 256, 0, stream>>>(EO, EO + (size_t)ROWS_ * 256, SIG);
    // sparse conv -> out
    dim3 gC(NS_ / 2048, B_ * NE_);
    conv_kernel<<<gC, 256, 0, stream>>>(SIG, CNT, TAPS, out);
}

// Round 8
// 107.760 us; speedup vs baseline: 2.4470x; 1.0935x over previous
//
#include <hip/hip_runtime.h>
#include <cstddef>

typedef unsigned short u16;
typedef __bf16 bf16x8 __attribute__((ext_vector_type(8)));
typedef float f32x4 __attribute__((ext_vector_type(4)));

// Problem constants
constexpr int B_   = 32;
constexpr int CTX_ = 128;
constexpr int NF_  = 128;     // frames
constexpr int NS_  = 32768;   // samples
constexpr int NE_  = 16;      // events
constexpr int CH_  = 256;
constexpr int NC_  = 257;     // coeffs
constexpr int TC_  = 514;     // 2*coeffs
constexpr int ROWS_ = B_ * NF_;  // 4096
constexpr int CHUNK_ = 8;        // frames per scan chunk
constexpr int NCH_ = NF_ / CHUNK_;  // 16 chunks
constexpr int KE_ = 288;         // parity-K for irfft (content 258/256, padded)
constexpr int K3MLP_ = 768;      // 3*256
constexpr int K3IR_ = 896;       // 3*288=864, padded to 64-mult
constexpr float PI_ = 3.14159265358979323846f;

__device__ __forceinline__ float lrelu(float v) { return v > 0.f ? v : 0.2f * v; }
__device__ __forceinline__ u16 f2bf(float x) {
    unsigned u = __float_as_uint(x);
    return (u16)((u + 0x7FFFu + ((u >> 16) & 1u)) >> 16);
}
__device__ __forceinline__ float bf2f(u16 h) { return __uint_as_float(((unsigned)h) << 16); }

// ============ prep: table3 | wconvu | compact | projstack, by block range ============
// blocks [0,1792): irfft triplet table   [1792,2880): weight triplets
// [2880,3392): tap compaction            [3392,3584): proj + pos stack
__global__ __launch_bounds__(256) void prep_kernel(
    const float* __restrict__ param, const float* __restrict__ pw,
    const float* __restrict__ pb, const float* __restrict__ pos,
    const float* __restrict__ w1, const float* __restrict__ w2,
    const float* __restrict__ wo, const float* __restrict__ times,
    u16* __restrict__ Tt3, u16* __restrict__ W1_3, u16* __restrict__ W2_3,
    u16* __restrict__ WO_3, int* __restrict__ cnt, float2* __restrict__ taps,
    float* __restrict__ S)
{
    int blk = blockIdx.x;
    int tid = threadIdx.x;
    if (blk < 1792) {
        // ---- irfft parity tables, per-element incl. pads ----
        int idx = blk * 256 + tid;
        int z = idx / (256 * K3IR_);
        int r = idx - z * (256 * K3IR_);
        int n = r / K3IR_, col = r - n * K3IR_;
        u16 outv = 0;
        if (col < 864) {
            int seg = col / KE_;
            int j = col - seg * KE_;
            float val = 0.f;
            if (z == 0) {
                if (j < 129) {
                    int k = 2 * j;
                    float w = (k == 0 || k == 256) ? 1.f : 2.f;
                    int m = (k * n) & 511;
                    val = w * (1.f / 512.f) * cosf((float)m * (PI_ / 256.f));
                } else if (j < 258) {
                    int kk = 2 * (j - 129);
                    float w = (kk == 0 || kk == 256) ? 1.f : 2.f;
                    int m = (kk * n) & 511;
                    val = -w * (1.f / 512.f) * sinf((float)m * (PI_ / 256.f));
                }
            } else {
                if (j < 128) {
                    int k = 2 * j + 1;
                    int m = (k * n) & 511;
                    val = 2.f * (1.f / 512.f) * cosf((float)m * (PI_ / 256.f));
                } else if (j < 256) {
                    int kk = 2 * (j - 128) + 1;
                    int m = (kk * n) & 511;
                    val = -2.f * (1.f / 512.f) * sinf((float)m * (PI_ / 256.f));
                }
            }
            u16 h = f2bf(val);
            outv = (seg < 2) ? h : f2bf(val - bf2f(h));
        }
        Tt3[idx] = outv;
    } else if (blk < 2880) {
        // ---- weight triplets (hi|hi|lo) ----
        int row = blk - 1792;        // 0..1087
        int k = tid;
        float v;
        u16* p;
        if (row < 256) {
            v = w1[row * 256 + k];
            p = W1_3 + (size_t)row * K3MLP_;
        } else if (row < 512) {
            v = w2[(row - 256) * 256 + k];
            p = W2_3 + (size_t)(row - 256) * K3MLP_;
        } else {
            int n = row - 512;       // 0..575, valid < 514
            v = (n < TC_) ? wo[n * 256 + k] : 0.f;
            p = WO_3 + (size_t)n * K3MLP_;
        }
        u16 h = f2bf(v), lo = f2bf(v - bf2f(h));
        p[k] = h; p[256 + k] = h; p[512 + k] = lo;
    } else if (blk < 3392) {
        // ---- tap compaction ----
        int be = blk - 2880;
        __shared__ int c;
        if (tid == 0) c = 0;
        __syncthreads();
        if (tid < NF_) {
            float v = times[(size_t)be * NF_ + tid];
            if (v != 0.f) {
                int slot = atomicAdd(&c, 1);
                taps[(size_t)be * NF_ + slot] = make_float2((float)tid, v);
            }
        }
        __syncthreads();
        if (tid == 0) cnt[be] = c;
    } else {
        // ---- proj + pos stack -> S ----
        int b = blk - 3392;      // 0..191
        int cth = tid;
        float v;
        if (b < 32) {
            const float* pr = param + b * CTX_;
            const float* wr = pw + cth * CTX_;
            float s = 0.f;
            #pragma unroll 4
            for (int j = 0; j < CTX_; ++j) s += pr[j] * wr[j];
            v = s + pb[cth];
        } else if (b < 160) {
            v = pos[(b - 32) * CH_ + cth];
        } else {
            v = 0.f;
        }
        S[b * CH_ + cth] = v;
    }
}

// ---------------- fp32 gemm (layer-1 only): C = A @ B^T, 64x64 tile, BK=32 ----------
__global__ __launch_bounds__(256) void gemm2(
    const float* __restrict__ A, const float* __restrict__ Bm, float* __restrict__ C,
    int M, int N, int K, int lda, int ldb, int ldc)
{
    const int tid = threadIdx.x;
    const int tx = tid & 15, ty = tid >> 4;
    const int m0 = blockIdx.y * 64, n0 = blockIdx.x * 64;
    __shared__ __align__(16) float As[32][64];
    __shared__ __align__(16) float Bs[32][64];
    const int ar = tid & 63, akg = (tid >> 6) * 8;
    float4 ra0, ra1, rb0, rb1;
    auto loadA = [&](int kt) {
        const float* p = A + (size_t)(m0 + ar) * lda + kt + akg;
        ra0 = *(const float4*)p; ra1 = *(const float4*)(p + 4);
    };
    auto loadB = [&](int kt) {
        const float* p = Bm + (size_t)(n0 + ar) * ldb + kt + akg;
        rb0 = *(const float4*)p; rb1 = *(const float4*)(p + 4);
    };
    loadA(0); loadB(0);
    float acc[4][4] = {};
    for (int kt = 0; kt < K; kt += 32) {
        As[akg+0][ar] = ra0.x; As[akg+1][ar] = ra0.y; As[akg+2][ar] = ra0.z; As[akg+3][ar] = ra0.w;
        As[akg+4][ar] = ra1.x; As[akg+5][ar] = ra1.y; As[akg+6][ar] = ra1.z; As[akg+7][ar] = ra1.w;
        Bs[akg+0][ar] = rb0.x; Bs[akg+1][ar] = rb0.y; Bs[akg+2][ar] = rb0.z; Bs[akg+3][ar] = rb0.w;
        Bs[akg+4][ar] = rb1.x; Bs[akg+5][ar] = rb1.y; Bs[akg+6][ar] = rb1.z; Bs[akg+7][ar] = rb1.w;
        __syncthreads();
        if (kt + 32 < K) { loadA(kt + 32); loadB(kt + 32); }
        #pragma unroll
        for (int kk = 0; kk < 32; ++kk) {
            float4 av = *(const float4*)&As[kk][ty*4];
            float4 bv = *(const float4*)&Bs[kk][tx*4];
            float a4[4] = {av.x, av.y, av.z, av.w};
            float b4[4] = {bv.x, bv.y, bv.z, bv.w};
            #pragma unroll
            for (int i = 0; i < 4; ++i)
                #pragma unroll
                for (int j = 0; j < 4; ++j)
                    acc[i][j] += a4[i] * b4[j];
        }
        __syncthreads();
    }
    #pragma unroll
    for (int i = 0; i < 4; ++i)
        #pragma unroll
        for (int j = 0; j < 4; ++j)
            C[(size_t)(m0 + ty*4 + i) * ldc + n0 + tx*4 + j] = acc[i][j];
}

// ---------------- fuse1: H1_3 triplet = lrelu(YP[b] + YP[32+f] + b0) ----------------
__global__ void fuse1_kernel(const float* __restrict__ YP, const float* __restrict__ b0,
                             u16* __restrict__ H3) {
    int idx = blockIdx.x * 256 + threadIdx.x;   // 4096*256
    int c = idx & 255;
    int row = idx >> 8;
    int b = row >> 7, f = row & 127;
    float v = lrelu(YP[b * CH_ + c] + YP[(32 + f) * CH_ + c] + b0[c]);
    u16 h = f2bf(v), lo = f2bf(v - bf2f(h));
    u16* p = H3 + (size_t)row * K3MLP_;
    p[c] = h; p[256 + c] = lo; p[512 + c] = h;
}

// ---------------- mfgemm: C = A3 @ B3^T, bf16-split MFMA, 64x64 tile, BK=64 ----------
// Depth-2 global prefetch (two named register sets, 2 K-steps per loop iter),
// double-buffered LDS, one barrier per K-step.
// EPI 0: bias+lrelu -> bf16 triplet; EPI 1: bias -> fp32 (N-guarded); EPI 2: fp32 z-batched.
template<int EPI, int K3>
__global__ __launch_bounds__(256) void mfgemm(
    const u16* __restrict__ A3, const u16* __restrict__ B3,
    const float* __restrict__ bias, void* __restrict__ Cout,
    int N, int lda, int ldb, int ldc,
    size_t sAz, size_t sBz, size_t sCz)
{
    A3 += (size_t)blockIdx.z * sAz;
    B3 += (size_t)blockIdx.z * sBz;
    const int tid = threadIdx.x;
    const int m0 = blockIdx.y * 64, n0 = blockIdx.x * 64;
    __shared__ __align__(16) u16 Als[2 * 64 * 64];
    __shared__ __align__(16) u16 Bls[2 * 64 * 64];
    const int sr = tid >> 2;
    const int sc = (tid & 3) * 16;                 // ushort offset
    const u16* ga = A3 + (size_t)(m0 + sr) * lda + sc;
    const u16* gb = B3 + (size_t)(n0 + sr) * ldb + sc;
    const int xr = (sr & 7) << 4;
    const int lo0 = sr * 128 + ((sc * 2) ^ xr);        // byte offset within buffer
    const int lo1 = sr * 128 + ((sc * 2 + 16) ^ xr);
    const int wv = tid >> 6, lane = tid & 63;
    const int wr = (wv >> 1) * 32, wc = (wv & 1) * 32;
    const int lr = lane & 15;
    const int lkb = (lane >> 4) * 16;
    const int xf = (lr & 7) << 4;
    const int ra0 = (wr + lr) * 128, ra1 = (wr + 16 + lr) * 128;
    const int rb0 = (wc + lr) * 128, rb1 = (wc + 16 + lr) * 128;
    f32x4 acc00 = {0.f, 0.f, 0.f, 0.f}, acc01 = acc00, acc10 = acc00, acc11 = acc00;

    uint4 pa0, pa1, pb0, pb1;   // set P
    uint4 qa0, qa1, qb0, qb1;   // set Q
    auto loadP = [&](int kt) {
        pa0 = *(const uint4*)(ga + kt); pa1 = *(const uint4*)(ga + kt + 8);
        pb0 = *(const uint4*)(gb + kt); pb1 = *(const uint4*)(gb + kt + 8);
    };
    auto loadQ = [&](int kt) {
        qa0 = *(const uint4*)(ga + kt); qa1 = *(const uint4*)(ga + kt + 8);
        qb0 = *(const uint4*)(gb + kt); qb1 = *(const uint4*)(gb + kt + 8);
    };
    auto compute = [&](int p) {
        const char* pa = (const char*)Als + p * 8192;
        const char* pb = (const char*)Bls + p * 8192;
        #pragma unroll
        for (int s = 0; s < 2; ++s) {
            int kb = (s * 64 + lkb) ^ xf;
            bf16x8 a0 = *(const bf16x8*)(pa + ra0 + kb);
            bf16x8 a1 = *(const bf16x8*)(pa + ra1 + kb);
            bf16x8 b0 = *(const bf16x8*)(pb + rb0 + kb);
            bf16x8 b1 = *(const bf16x8*)(pb + rb1 + kb);
            acc00 = __builtin_amdgcn_mfma_f32_16x16x32_bf16(a0, b0, acc00, 0, 0, 0);
            acc01 = __builtin_amdgcn_mfma_f32_16x16x32_bf16(a0, b1, acc01, 0, 0, 0);
            acc10 = __builtin_amdgcn_mfma_f32_16x16x32_bf16(a1, b0, acc10, 0, 0, 0);
            acc11 = __builtin_amdgcn_mfma_f32_16x16x32_bf16(a1, b1, acc11, 0, 0, 0);
        }
    };
    loadP(0);
    loadQ(64);
    int p = 0;
    #pragma unroll
    for (int kt = 0; kt < K3; kt += 128) {
        // step kt (set P)
        {
            char* ab = (char*)Als + p * 8192;
            char* bb = (char*)Bls + p * 8192;
            *(uint4*)(ab + lo0) = pa0; *(uint4*)(ab + lo1) = pa1;
            *(uint4*)(bb + lo0) = pb0; *(uint4*)(bb + lo1) = pb1;
            __syncthreads();
            if (kt + 128 < K3) loadP(kt + 128);
            compute(p);
            p ^= 1;
        }
        // step kt+64 (set Q)
        {
            char* ab = (char*)Als + p * 8192;
            char* bb = (char*)Bls + p * 8192;
            *(uint4*)(ab + lo0) = qa0; *(uint4*)(ab + lo1) = qa1;
            *(uint4*)(bb + lo0) = qb0; *(uint4*)(bb + lo1) = qb1;
            __syncthreads();
            if (kt + 192 < K3) loadQ(kt + 192);
            compute(p);
            p ^= 1;
        }
    }
    const int er = (lane >> 4) * 4;
    const int ec = lane & 15;
    auto emit = [&](const f32x4& A, int mi, int ni) {
        #pragma unroll
        for (int r = 0; r < 4; ++r) {
            int m = m0 + wr + mi * 16 + er + r;
            int n = n0 + wc + ni * 16 + ec;
            float v = A[r];
            if (EPI == 0) {
                v = lrelu(v + bias[n]);
                u16 h = f2bf(v), lo = f2bf(v - bf2f(h));
                u16* p2 = (u16*)Cout + (size_t)m * ldc + n;
                p2[0] = h; p2[256] = lo; p2[512] = h;
            } else if (EPI == 1) {
                if (n < N) ((float*)Cout)[(size_t)m * ldc + n] = v + bias[n];
            } else {
                float* cf = (float*)Cout + (size_t)blockIdx.z * sCz;
                cf[(size_t)m * ldc + n] = v;
            }
        }
    };
    emit(acc00, 0, 0); emit(acc01, 0, 1); emit(acc10, 1, 0); emit(acc11, 1, 1);
}

// ---------------- scan pass 1: per-chunk sum of dphi (double) ----------------
__global__ void scan1_kernel(const float* __restrict__ raw, const float* __restrict__ noise,
                             double* __restrict__ sums) {
    int b = blockIdx.x, c = blockIdx.y;
    int k = threadIdx.x;
    if (k >= NC_) return;
    float kf = (float)k * (PI_ / 256.f);
    double s = 0.0;
    #pragma unroll
    for (int j = 0; j < CHUNK_; ++j) {
        int row = b * NF_ + c * CHUNK_ + j;
        float2 v = *(const float2*)(raw + (size_t)row * TC_ + 2 * k);
        float d = (1.f + v.y * noise[(size_t)row * NC_ + k]) * kf;
        s += (double)d;
    }
    sums[((size_t)(b * NCH_ + c)) * NC_ + k] = s;
}

// ---------------- scan pass 2: prefix + sincos -> parity triplets; pads inline --------
__global__ void scan2_kernel(const float* __restrict__ raw, const float* __restrict__ noise,
                             const double* __restrict__ sums,
                             u16* __restrict__ AB3e, u16* __restrict__ AB3o) {
    int b = blockIdx.x, c = blockIdx.y;
    int k = threadIdx.x;
    if (k >= NC_) {
        int t = k - NC_;   // 0..62
        for (int idx = t; idx < 250; idx += 63) {
            int col;
            u16* base;
            if (idx < 122) {
                col = (idx < 90) ? ((idx / 30) * KE_ + 258 + (idx % 30)) : (864 + (idx - 90));
                base = AB3e;
            } else {
                int u = idx - 122;
                col = (u < 96) ? ((u / 32) * KE_ + 256 + (u % 32)) : (864 + (u - 96));
                base = AB3o;
            }
            for (int j = 0; j < CHUNK_; ++j)
                base[(size_t)(b * NF_ + c * CHUNK_ + j) * K3IR_ + col] = 0;
        }
        return;
    }
    double p = 0.0;
    for (int cc = 0; cc < c; ++cc)
        p += sums[((size_t)(b * NCH_ + cc)) * NC_ + k];
    float kf = (float)k * (PI_ / 256.f);
    int half = k >> 1;
    bool even = (k & 1) == 0;
    int ccol = half;
    int scol = even ? (129 + half) : (128 + half);
    u16* dst = even ? AB3e : AB3o;
    for (int j = 0; j < CHUNK_; ++j) {
        int row = b * NF_ + c * CHUNK_ + j;
        float2 v = *(const float2*)(raw + (size_t)row * TC_ + 2 * k);
        float d = (1.f + v.y * noise[(size_t)row * NC_ + k]) * kf;
        p += (double)d;
        float m = fabsf(v.x);
        float sn, cs;
        sincosf((float)p, &sn, &cs);
        float a = m * cs, bb = m * sn;
        u16* pr = dst + (size_t)row * K3IR_;
        u16 ha = f2bf(a), la = f2bf(a - bf2f(ha));
        pr[ccol] = ha; pr[KE_ + ccol] = la; pr[2 * KE_ + ccol] = ha;
        u16 hb = f2bf(bb), lb = f2bf(bb - bf2f(hb));
        pr[scol] = hb; pr[KE_ + scol] = lb; pr[2 * KE_ + scol] = hb;
    }
}

// ---------------- conv2: sparse conv with inline OLA (sig computed from E/O) ---------
// sig[b][s] = hr[r]*(E[q][r]+O[q][r]) + (q>0)*hr2[r]*(E[q-1][r]-O[q-1][r]), s=q*256+r.
// All 8 samples of a thread share r-block (t mod 256 in [0,248]).
__global__ __launch_bounds__(256) void conv2_kernel(const float* __restrict__ E,
                                                    const float* __restrict__ O,
                                                    const int* __restrict__ cnt,
                                                    const float2* __restrict__ taps,
                                                    float* __restrict__ out) {
    int be = blockIdx.y;
    int b = be >> 4;
    int n = cnt[be];
    int t = blockIdx.x * 2048 + (int)threadIdx.x * 8;
    int r0 = t & 255;
    float hr[8], hr2[8];
    #pragma unroll
    for (int j = 0; j < 8; ++j) {
        float cj = cosf((float)(r0 + j) * (PI_ / 256.f));
        hr[j]  = 0.5f - 0.5f * cj;
        hr2[j] = 0.5f + 0.5f * cj;
    }
    float acc[8] = {};
    for (int i = 0; i < n; ++i) {
        float2 ka = taps[(size_t)be * NF_ + i];
        int s0 = t - ((int)ka.x << 8);
        if (s0 < 0) continue;
        float amp = ka.y;
        int q = s0 >> 8;
        size_t row = (size_t)(b * NF_ + q) * 256 + r0;
        float4 e0 = *(const float4*)(E + row);
        float4 e1 = *(const float4*)(E + row + 4);
        float4 o0 = *(const float4*)(O + row);
        float4 o1 = *(const float4*)(O + row + 4);
        float sv[8];
        sv[0] = hr[0] * (e0.x + o0.x); sv[1] = hr[1] * (e0.y + o0.y);
        sv[2] = hr[2] * (e0.z + o0.z); sv[3] = hr[3] * (e0.w + o0.w);
        sv[4] = hr[4] * (e1.x + o1.x); sv[5] = hr[5] * (e1.y + o1.y);
        sv[6] = hr[6] * (e1.z + o1.z); sv[7] = hr[7] * (e1.w + o1.w);
        if (q > 0) {
            float4 pe0 = *(const float4*)(E + row - 256);
            float4 pe1 = *(const float4*)(E + row - 252);
            float4 po0 = *(const float4*)(O + row - 256);
            float4 po1 = *(const float4*)(O + row - 252);
            sv[0] += hr2[0] * (pe0.x - po0.x); sv[1] += hr2[1] * (pe0.y - po0.y);
            sv[2] += hr2[2] * (pe0.z - po0.z); sv[3] += hr2[3] * (pe0.w - po0.w);
            sv[4] += hr2[4] * (pe1.x - po1.x); sv[5] += hr2[5] * (pe1.y - po1.y);
            sv[6] += hr2[6] * (pe1.z - po1.z); sv[7] += hr2[7] * (pe1.w - po1.w);
        }
        #pragma unroll
        for (int j = 0; j < 8; ++j) acc[j] += amp * sv[j];
    }
    float* op = out + (size_t)be * NS_ + t;
    float4 w0v = make_float4(acc[0], acc[1], acc[2], acc[3]);
    float4 w1v = make_float4(acc[4], acc[5], acc[6], acc[7]);
    *(float4*)op = w0v;
    *(float4*)(op + 4) = w1v;
}

extern "C" void kernel_launch(void* const* d_in, const int* in_sizes, int n_in,
                              void* d_out, int out_size, void* d_ws, size_t ws_size,
                              hipStream_t stream) {
    const float* param  = (const float*)d_in[0];
    const float* times  = (const float*)d_in[1];
    const float* noise  = (const float*)d_in[2];
    const float* pos    = (const float*)d_in[3];
    const float* proj_w = (const float*)d_in[4];
    const float* proj_b = (const float*)d_in[5];
    const float* w0 = (const float*)d_in[6];
    const float* b0 = (const float*)d_in[7];
    const float* w1 = (const float*)d_in[8];
    const float* b1 = (const float*)d_in[9];
    const float* w2 = (const float*)d_in[10];
    const float* b2 = (const float*)d_in[11];
    const float* w_out = (const float*)d_in[12];
    const float* b_out = (const float*)d_in[13];
    float* out = (float*)d_out;
    float* ws = (float*)d_ws;

    // ws layout — cursor in FLOAT units; u16 buffers consume (u16_count/2) floats.
    constexpr size_t S_F    = 192 * 256;
    constexpr size_t YP_F   = 192 * 256;
    constexpr size_t H3_F   = (size_t)ROWS_ * K3MLP_ / 2;
    constexpr size_t W3_F   = (size_t)256 * K3MLP_ / 2;
    constexpr size_t WO3_F  = (size_t)576 * K3MLP_ / 2;
    constexpr size_t RAW_F  = (size_t)ROWS_ * TC_;
    constexpr size_t AB3_F  = 2 * (size_t)ROWS_ * K3IR_ / 2;
    constexpr size_t TT3_F  = 2 * (size_t)256 * K3IR_ / 2;
    constexpr size_t EO_F   = 2 * (size_t)ROWS_ * 256;
    constexpr size_t SUMS_F = (size_t)B_ * NCH_ * NC_ * 2;

    size_t cur = 0;
    float* S    = ws + cur;                 cur += S_F;
    float* YP   = ws + cur;                 cur += YP_F;
    u16*  H1_3  = (u16*)(ws + cur);         cur += H3_F;
    u16*  H2_3  = (u16*)(ws + cur);         cur += H3_F;
    u16*  H3_3  = (u16*)(ws + cur);         cur += H3_F;
    u16*  W1_3  = (u16*)(ws + cur);         cur += W3_F;
    u16*  W2_3  = (u16*)(ws + cur);         cur += W3_F;
    u16*  WO_3  = (u16*)(ws + cur);         cur += WO3_F;
    float* RAW  = ws + cur;                 cur += RAW_F;
    u16*  AB3   = (u16*)(ws + cur);         cur += AB3_F;
    u16*  AB3e  = AB3;
    u16*  AB3o  = AB3 + (size_t)ROWS_ * K3IR_;
    u16*  Tt3   = (u16*)(ws + cur);         cur += TT3_F;
    float* EO   = ws + cur;                 cur += EO_F;
    double* SUMS = (double*)(ws + cur);     cur += SUMS_F;
    int*   CNT  = (int*)(ws + cur);         cur += 512;
    float2* TAPS = (float2*)(ws + cur);     // 512*128 float2

    // 1) fused prep: tables + weight triplets + tap compaction + proj/stack
    prep_kernel<<<3584, 256, 0, stream>>>(param, proj_w, proj_b, pos, w1, w2, w_out,
                                          times, Tt3, W1_3, W2_3, WO_3, CNT, TAPS, S);
    // 2) layer-1 collapse (fp32): YP = S @ w0^T (192x256x256)
    gemm2<<<dim3(4, 3, 1), 256, 0, stream>>>(S, w0, YP, 192, CH_, CH_, CH_, CH_, CH_);
    fuse1_kernel<<<ROWS_ * CH_ / 256, 256, 0, stream>>>(YP, b0, H1_3);
    // 3) MLP layers 2,3 (bf16-split MFMA, depth-2 prefetch)
    mfgemm<0, K3MLP_><<<dim3(4, 64, 1), 256, 0, stream>>>(H1_3, W1_3, b1, H2_3, 256,
                                                          K3MLP_, K3MLP_, K3MLP_, 0, 0, 0);
    mfgemm<0, K3MLP_><<<dim3(4, 64, 1), 256, 0, stream>>>(H2_3, W2_3, b2, H3_3, 256,
                                                          K3MLP_, K3MLP_, K3MLP_, 0, 0, 0);
    // 4) output layer -> RAW fp32 (bias, N=514 guarded)
    mfgemm<1, K3MLP_><<<dim3(9, 64, 1), 256, 0, stream>>>(H3_3, WO_3, b_out, RAW, TC_,
                                                          K3MLP_, K3MLP_, TC_, 0, 0, 0);
    // 5) phase scan (double carry) -> AB3 triplets (pads by spare threads)
    dim3 gS(B_, NCH_);
    scan1_kernel<<<gS, 320, 0, stream>>>(RAW, noise, SUMS);
    scan2_kernel<<<gS, 320, 0, stream>>>(RAW, noise, SUMS, AB3e, AB3o);
    // 6) parity irfft (z-batched): EO[z] = AB3[z] @ Tt3[z]^T
    mfgemm<2, K3IR_><<<dim3(4, 64, 2), 256, 0, stream>>>(AB3, Tt3, nullptr, EO, 256,
                                                         K3IR_, K3IR_, 256,
                                                         (size_t)ROWS_ * K3IR_,
                                                         (size_t)256 * K3IR_,
                                                         (size_t)ROWS_ * 256);
    // 7) sparse conv with inline overlap-add/hann -> out
    dim3 gC(NS_ / 2048, B_ * NE_);
    conv2_kernel<<<gC, 256, 0, stream>>>(EO, EO + (size_t)ROWS_ * 256, CNT, TAPS, out);
}

// Round 9
// 106.400 us; speedup vs baseline: 2.4783x; 1.0128x over previous
//
#include <hip/hip_runtime.h>
#include <cstddef>

typedef unsigned short u16;
typedef __bf16 bf16x8 __attribute__((ext_vector_type(8)));
typedef float f32x4 __attribute__((ext_vector_type(4)));

// Problem constants
constexpr int B_   = 32;
constexpr int CTX_ = 128;
constexpr int NF_  = 128;     // frames
constexpr int NS_  = 32768;   // samples
constexpr int NE_  = 16;      // events
constexpr int CH_  = 256;
constexpr int NC_  = 257;     // coeffs
constexpr int TC_  = 514;     // 2*coeffs
constexpr int ROWS_ = B_ * NF_;  // 4096
constexpr int CHUNK_ = 8;        // frames per scan chunk
constexpr int NCH_ = NF_ / CHUNK_;  // 16 chunks
constexpr int KE_ = 288;         // parity-K for irfft (content 258/256, padded)
constexpr int K3MLP_ = 768;      // 3*256
constexpr int K3IR_ = 896;       // 3*288=864, padded to 64-mult
constexpr float PI_ = 3.14159265358979323846f;

__device__ __forceinline__ float lrelu(float v) { return v > 0.f ? v : 0.2f * v; }
__device__ __forceinline__ u16 f2bf(float x) {
    unsigned u = __float_as_uint(x);
    return (u16)((u + 0x7FFFu + ((u >> 16) & 1u)) >> 16);
}
__device__ __forceinline__ float bf2f(u16 h) { return __uint_as_float(((unsigned)h) << 16); }

// ============ prep: table3 | wconvu | compact | U | V, by block range ============
// [0,1792): irfft triplet table    [1792,2880): weight triplets
// [2880,3392): tap compaction      [3392,3424): U = (param@pw^T+pb)@w0^T (32 rows)
// [3424,3552): V = pos@w0^T (128 rows)
__global__ __launch_bounds__(256) void prep_kernel(
    const float* __restrict__ param, const float* __restrict__ pw,
    const float* __restrict__ pb, const float* __restrict__ pos,
    const float* __restrict__ w0, const float* __restrict__ w1,
    const float* __restrict__ w2, const float* __restrict__ wo,
    const float* __restrict__ times,
    u16* __restrict__ Tt3, u16* __restrict__ W1_3, u16* __restrict__ W2_3,
    u16* __restrict__ WO_3, int* __restrict__ cnt, float2* __restrict__ taps,
    float* __restrict__ U, float* __restrict__ V)
{
    int blk = blockIdx.x;
    int tid = threadIdx.x;
    if (blk < 1792) {
        // ---- irfft parity tables, per-element incl. pads ----
        int idx = blk * 256 + tid;
        int z = idx / (256 * K3IR_);
        int r = idx - z * (256 * K3IR_);
        int n = r / K3IR_, col = r - n * K3IR_;
        u16 outv = 0;
        if (col < 864) {
            int seg = col / KE_;
            int j = col - seg * KE_;
            float val = 0.f;
            if (z == 0) {
                if (j < 129) {
                    int k = 2 * j;
                    float w = (k == 0 || k == 256) ? 1.f : 2.f;
                    int m = (k * n) & 511;
                    val = w * (1.f / 512.f) * cosf((float)m * (PI_ / 256.f));
                } else if (j < 258) {
                    int kk = 2 * (j - 129);
                    float w = (kk == 0 || kk == 256) ? 1.f : 2.f;
                    int m = (kk * n) & 511;
                    val = -w * (1.f / 512.f) * sinf((float)m * (PI_ / 256.f));
                }
            } else {
                if (j < 128) {
                    int k = 2 * j + 1;
                    int m = (k * n) & 511;
                    val = 2.f * (1.f / 512.f) * cosf((float)m * (PI_ / 256.f));
                } else if (j < 256) {
                    int kk = 2 * (j - 128) + 1;
                    int m = (kk * n) & 511;
                    val = -2.f * (1.f / 512.f) * sinf((float)m * (PI_ / 256.f));
                }
            }
            u16 h = f2bf(val);
            outv = (seg < 2) ? h : f2bf(val - bf2f(h));
        }
        Tt3[idx] = outv;
    } else if (blk < 2880) {
        // ---- weight triplets (hi|hi|lo) ----
        int row = blk - 1792;        // 0..1087
        int k = tid;
        float v;
        u16* p;
        if (row < 256) {
            v = w1[row * 256 + k];
            p = W1_3 + (size_t)row * K3MLP_;
        } else if (row < 512) {
            v = w2[(row - 256) * 256 + k];
            p = W2_3 + (size_t)(row - 256) * K3MLP_;
        } else {
            int n = row - 512;       // 0..575, valid < 514
            v = (n < TC_) ? wo[n * 256 + k] : 0.f;
            p = WO_3 + (size_t)n * K3MLP_;
        }
        u16 h = f2bf(v), lo = f2bf(v - bf2f(h));
        p[k] = h; p[256 + k] = h; p[512 + k] = lo;
    } else if (blk < 3392) {
        // ---- tap compaction ----
        int be = blk - 2880;
        __shared__ int c;
        if (tid == 0) c = 0;
        __syncthreads();
        if (tid < NF_) {
            float v = times[(size_t)be * NF_ + tid];
            if (v != 0.f) {
                int slot = atomicAdd(&c, 1);
                taps[(size_t)be * NF_ + slot] = make_float2((float)tid, v);
            }
        }
        __syncthreads();
        if (tid == 0) cnt[be] = c;
    } else if (blk < 3424) {
        // ---- U rows: recompute y0[b] in LDS, then U[b][n] = y0 . w0[n] ----
        int b = blk - 3392;      // 0..31
        __shared__ float ly[256];
        {
            const float* pr = param + b * CTX_;
            const float* wr = pw + tid * CTX_;
            float s = 0.f;
            #pragma unroll 4
            for (int j = 0; j < CTX_; ++j) s += pr[j] * wr[j];
            ly[tid] = s + pb[tid];
        }
        __syncthreads();
        {
            const float* wn = w0 + tid * CH_;
            float s = 0.f;
            #pragma unroll 4
            for (int c2 = 0; c2 < CH_; ++c2) s += ly[c2] * wn[c2];
            U[b * CH_ + tid] = s;
        }
    } else {
        // ---- V rows: V[f][n] = pos[f] . w0[n] ----
        int f = blk - 3424;      // 0..127
        const float* pf = pos + f * CH_;
        const float* wn = w0 + tid * CH_;
        float s = 0.f;
        #pragma unroll 4
        for (int c2 = 0; c2 < CH_; ++c2) s += pf[c2] * wn[c2];
        V[f * CH_ + tid] = s;
    }
}

// ---------------- fuse1: H1_3 triplet = lrelu(U[b] + V[f] + b0) ----------------
__global__ void fuse1_kernel(const float* __restrict__ U, const float* __restrict__ V,
                             const float* __restrict__ b0, u16* __restrict__ H3) {
    int idx = blockIdx.x * 256 + threadIdx.x;   // 4096*256
    int c = idx & 255;
    int row = idx >> 8;
    int b = row >> 7, f = row & 127;
    float v = lrelu(U[b * CH_ + c] + V[f * CH_ + c] + b0[c]);
    u16 h = f2bf(v), lo = f2bf(v - bf2f(h));
    u16* p = H3 + (size_t)row * K3MLP_;
    p[c] = h; p[256 + c] = lo; p[512 + c] = h;
}

// ---------------- mfgemm: C = A3 @ B3^T, bf16-split MFMA, 32x64 tile, BK=64 ----------
// 128 threads (2 waves), depth-2 global prefetch, double-buffered LDS, 24KB LDS
// -> 4+ blocks/CU for latency hiding via TLP.
// EPI 0: bias+lrelu -> bf16 triplet; EPI 1: bias -> fp32 (N-guarded); EPI 2: fp32 z-batched.
template<int EPI, int K3>
__global__ __launch_bounds__(128) void mfgemm(
    const u16* __restrict__ A3, const u16* __restrict__ B3,
    const float* __restrict__ bias, void* __restrict__ Cout,
    int N, int lda, int ldb, int ldc,
    size_t sAz, size_t sBz, size_t sCz)
{
    A3 += (size_t)blockIdx.z * sAz;
    B3 += (size_t)blockIdx.z * sBz;
    const int tid = threadIdx.x;
    const int m0 = blockIdx.y * 32, n0 = blockIdx.x * 64;
    __shared__ __align__(16) u16 Als[2 * 32 * 64];   //  8KB
    __shared__ __align__(16) u16 Bls[2 * 64 * 64];   // 16KB
    // staging maps: sr = tid>>2 (0..31), sc = (tid&3)*16 (u16 units)
    const int sr = tid >> 2;
    const int sc = (tid & 3) * 16;
    const u16* ga  = A3 + (size_t)(m0 + sr) * lda + sc;            // A row sr
    const u16* gb0 = B3 + (size_t)(n0 + sr) * ldb + sc;            // B row sr
    const u16* gb1 = B3 + (size_t)(n0 + 32 + sr) * ldb + sc;       // B row sr+32
    const int xr = (sr & 7) << 4;                                  // (sr+32)&7 == sr&7
    const int loA0 = sr * 128 + ((sc * 2) ^ xr);
    const int loA1 = sr * 128 + ((sc * 2 + 16) ^ xr);
    const int loB0 = sr * 128 + ((sc * 2) ^ xr);
    const int loB1 = sr * 128 + ((sc * 2 + 16) ^ xr);
    const int loB2 = (sr + 32) * 128 + ((sc * 2) ^ xr);
    const int loB3 = (sr + 32) * 128 + ((sc * 2 + 16) ^ xr);
    // fragment maps: 2 waves, each 32(M) x 32(N)
    const int wv = tid >> 6, lane = tid & 63;
    const int wc = wv * 32;
    const int lr = lane & 15;
    const int lkb = (lane >> 4) * 16;
    const int xf = (lr & 7) << 4;
    const int raf0 = lr * 128, raf1 = (16 + lr) * 128;
    const int rbf0 = (wc + lr) * 128, rbf1 = (wc + 16 + lr) * 128;
    f32x4 acc00 = {0.f, 0.f, 0.f, 0.f}, acc01 = acc00, acc10 = acc00, acc11 = acc00;

    uint4 pa0, pa1, pb0, pb1, pb2, pb3;   // set P
    uint4 qa0, qa1, qb0, qb1, qb2, qb3;   // set Q
    auto loadP = [&](int kt) {
        pa0 = *(const uint4*)(ga + kt);  pa1 = *(const uint4*)(ga + kt + 8);
        pb0 = *(const uint4*)(gb0 + kt); pb1 = *(const uint4*)(gb0 + kt + 8);
        pb2 = *(const uint4*)(gb1 + kt); pb3 = *(const uint4*)(gb1 + kt + 8);
    };
    auto loadQ = [&](int kt) {
        qa0 = *(const uint4*)(ga + kt);  qa1 = *(const uint4*)(ga + kt + 8);
        qb0 = *(const uint4*)(gb0 + kt); qb1 = *(const uint4*)(gb0 + kt + 8);
        qb2 = *(const uint4*)(gb1 + kt); qb3 = *(const uint4*)(gb1 + kt + 8);
    };
    auto compute = [&](int p) {
        const char* pa = (const char*)Als + p * 4096;
        const char* pb = (const char*)Bls + p * 8192;
        #pragma unroll
        for (int s = 0; s < 2; ++s) {
            int kb = (s * 64 + lkb) ^ xf;
            bf16x8 a0 = *(const bf16x8*)(pa + raf0 + kb);
            bf16x8 a1 = *(const bf16x8*)(pa + raf1 + kb);
            bf16x8 b0 = *(const bf16x8*)(pb + rbf0 + kb);
            bf16x8 b1 = *(const bf16x8*)(pb + rbf1 + kb);
            acc00 = __builtin_amdgcn_mfma_f32_16x16x32_bf16(a0, b0, acc00, 0, 0, 0);
            acc01 = __builtin_amdgcn_mfma_f32_16x16x32_bf16(a0, b1, acc01, 0, 0, 0);
            acc10 = __builtin_amdgcn_mfma_f32_16x16x32_bf16(a1, b0, acc10, 0, 0, 0);
            acc11 = __builtin_amdgcn_mfma_f32_16x16x32_bf16(a1, b1, acc11, 0, 0, 0);
        }
    };
    auto stage = [&](int p, const uint4& a0, const uint4& a1, const uint4& b0,
                     const uint4& b1, const uint4& b2, const uint4& b3) {
        char* ab = (char*)Als + p * 4096;
        char* bb = (char*)Bls + p * 8192;
        *(uint4*)(ab + loA0) = a0; *(uint4*)(ab + loA1) = a1;
        *(uint4*)(bb + loB0) = b0; *(uint4*)(bb + loB1) = b1;
        *(uint4*)(bb + loB2) = b2; *(uint4*)(bb + loB3) = b3;
    };
    loadP(0);
    loadQ(64);
    int p = 0;
    #pragma unroll
    for (int kt = 0; kt < K3; kt += 128) {
        // step kt (set P)
        stage(p, pa0, pa1, pb0, pb1, pb2, pb3);
        __syncthreads();
        if (kt + 128 < K3) loadP(kt + 128);
        compute(p);
        p ^= 1;
        // step kt+64 (set Q)
        stage(p, qa0, qa1, qb0, qb1, qb2, qb3);
        __syncthreads();
        if (kt + 192 < K3) loadQ(kt + 192);
        compute(p);
        p ^= 1;
    }
    const int er = (lane >> 4) * 4;
    const int ec = lane & 15;
    auto emit = [&](const f32x4& A, int mi, int ni) {
        #pragma unroll
        for (int r = 0; r < 4; ++r) {
            int m = m0 + mi * 16 + er + r;
            int n = n0 + wc + ni * 16 + ec;
            float v = A[r];
            if (EPI == 0) {
                v = lrelu(v + bias[n]);
                u16 h = f2bf(v), lo = f2bf(v - bf2f(h));
                u16* p2 = (u16*)Cout + (size_t)m * ldc + n;
                p2[0] = h; p2[256] = lo; p2[512] = h;
            } else if (EPI == 1) {
                if (n < N) ((float*)Cout)[(size_t)m * ldc + n] = v + bias[n];
            } else {
                float* cf = (float*)Cout + (size_t)blockIdx.z * sCz;
                cf[(size_t)m * ldc + n] = v;
            }
        }
    };
    emit(acc00, 0, 0); emit(acc01, 0, 1); emit(acc10, 1, 0); emit(acc11, 1, 1);
}

// ---------------- scan pass 1: per-chunk sum of dphi (double) ----------------
__global__ void scan1_kernel(const float* __restrict__ raw, const float* __restrict__ noise,
                             double* __restrict__ sums) {
    int b = blockIdx.x, c = blockIdx.y;
    int k = threadIdx.x;
    if (k >= NC_) return;
    float kf = (float)k * (PI_ / 256.f);
    double s = 0.0;
    #pragma unroll
    for (int j = 0; j < CHUNK_; ++j) {
        int row = b * NF_ + c * CHUNK_ + j;
        float2 v = *(const float2*)(raw + (size_t)row * TC_ + 2 * k);
        float d = (1.f + v.y * noise[(size_t)row * NC_ + k]) * kf;
        s += (double)d;
    }
    sums[((size_t)(b * NCH_ + c)) * NC_ + k] = s;
}

// ---------------- scan pass 2: prefix + sincos -> parity triplets; pads inline --------
__global__ void scan2_kernel(const float* __restrict__ raw, const float* __restrict__ noise,
                             const double* __restrict__ sums,
                             u16* __restrict__ AB3e, u16* __restrict__ AB3o) {
    int b = blockIdx.x, c = blockIdx.y;
    int k = threadIdx.x;
    if (k >= NC_) {
        int t = k - NC_;   // 0..62
        for (int idx = t; idx < 250; idx += 63) {
            int col;
            u16* base;
            if (idx < 122) {
                col = (idx < 90) ? ((idx / 30) * KE_ + 258 + (idx % 30)) : (864 + (idx - 90));
                base = AB3e;
            } else {
                int u = idx - 122;
                col = (u < 96) ? ((u / 32) * KE_ + 256 + (u % 32)) : (864 + (u - 96));
                base = AB3o;
            }
            for (int j = 0; j < CHUNK_; ++j)
                base[(size_t)(b * NF_ + c * CHUNK_ + j) * K3IR_ + col] = 0;
        }
        return;
    }
    double p = 0.0;
    for (int cc = 0; cc < c; ++cc)
        p += sums[((size_t)(b * NCH_ + cc)) * NC_ + k];
    float kf = (float)k * (PI_ / 256.f);
    int half = k >> 1;
    bool even = (k & 1) == 0;
    int ccol = half;
    int scol = even ? (129 + half) : (128 + half);
    u16* dst = even ? AB3e : AB3o;
    for (int j = 0; j < CHUNK_; ++j) {
        int row = b * NF_ + c * CHUNK_ + j;
        float2 v = *(const float2*)(raw + (size_t)row * TC_ + 2 * k);
        float d = (1.f + v.y * noise[(size_t)row * NC_ + k]) * kf;
        p += (double)d;
        float m = fabsf(v.x);
        float sn, cs;
        sincosf((float)p, &sn, &cs);
        float a = m * cs, bb = m * sn;
        u16* pr = dst + (size_t)row * K3IR_;
        u16 ha = f2bf(a), la = f2bf(a - bf2f(ha));
        pr[ccol] = ha; pr[KE_ + ccol] = la; pr[2 * KE_ + ccol] = ha;
        u16 hb = f2bf(bb), lb = f2bf(bb - bf2f(hb));
        pr[scol] = hb; pr[KE_ + scol] = lb; pr[2 * KE_ + scol] = hb;
    }
}

// ---------------- conv2: sparse conv with inline OLA (sig computed from E/O) ---------
__global__ __launch_bounds__(256) void conv2_kernel(const float* __restrict__ E,
                                                    const float* __restrict__ O,
                                                    const int* __restrict__ cnt,
                                                    const float2* __restrict__ taps,
                                                    float* __restrict__ out) {
    int be = blockIdx.y;
    int b = be >> 4;
    int n = cnt[be];
    int t = blockIdx.x * 2048 + (int)threadIdx.x * 8;
    int r0 = t & 255;
    float hr[8], hr2[8];
    #pragma unroll
    for (int j = 0; j < 8; ++j) {
        float cj = cosf((float)(r0 + j) * (PI_ / 256.f));
        hr[j]  = 0.5f - 0.5f * cj;
        hr2[j] = 0.5f + 0.5f * cj;
    }
    float acc[8] = {};
    for (int i = 0; i < n; ++i) {
        float2 ka = taps[(size_t)be * NF_ + i];
        int s0 = t - ((int)ka.x << 8);
        if (s0 < 0) continue;
        float amp = ka.y;
        int q = s0 >> 8;
        size_t row = (size_t)(b * NF_ + q) * 256 + r0;
        float4 e0 = *(const float4*)(E + row);
        float4 e1 = *(const float4*)(E + row + 4);
        float4 o0 = *(const float4*)(O + row);
        float4 o1 = *(const float4*)(O + row + 4);
        float sv[8];
        sv[0] = hr[0] * (e0.x + o0.x); sv[1] = hr[1] * (e0.y + o0.y);
        sv[2] = hr[2] * (e0.z + o0.z); sv[3] = hr[3] * (e0.w + o0.w);
        sv[4] = hr[4] * (e1.x + o1.x); sv[5] = hr[5] * (e1.y + o1.y);
        sv[6] = hr[6] * (e1.z + o1.z); sv[7] = hr[7] * (e1.w + o1.w);
        if (q > 0) {
            float4 pe0 = *(const float4*)(E + row - 256);
            float4 pe1 = *(const float4*)(E + row - 252);
            float4 po0 = *(const float4*)(O + row - 256);
            float4 po1 = *(const float4*)(O + row - 252);
            sv[0] += hr2[0] * (pe0.x - po0.x); sv[1] += hr2[1] * (pe0.y - po0.y);
            sv[2] += hr2[2] * (pe0.z - po0.z); sv[3] += hr2[3] * (pe0.w - po0.w);
            sv[4] += hr2[4] * (pe1.x - po1.x); sv[5] += hr2[5] * (pe1.y - po1.y);
            sv[6] += hr2[6] * (pe1.z - po1.z); sv[7] += hr2[7] * (pe1.w - po1.w);
        }
        #pragma unroll
        for (int j = 0; j < 8; ++j) acc[j] += amp * sv[j];
    }
    float* op = out + (size_t)be * NS_ + t;
    *(float4*)op = make_float4(acc[0], acc[1], acc[2], acc[3]);
    *(float4*)(op + 4) = make_float4(acc[4], acc[5], acc[6], acc[7]);
}

extern "C" void kernel_launch(void* const* d_in, const int* in_sizes, int n_in,
                              void* d_out, int out_size, void* d_ws, size_t ws_size,
                              hipStream_t stream) {
    const float* param  = (const float*)d_in[0];
    const float* times  = (const float*)d_in[1];
    const float* noise  = (const float*)d_in[2];
    const float* pos    = (const float*)d_in[3];
    const float* proj_w = (const float*)d_in[4];
    const float* proj_b = (const float*)d_in[5];
    const float* w0 = (const float*)d_in[6];
    const float* b0 = (const float*)d_in[7];
    const float* w1 = (const float*)d_in[8];
    const float* b1 = (const float*)d_in[9];
    const float* w2 = (const float*)d_in[10];
    const float* b2 = (const float*)d_in[11];
    const float* w_out = (const float*)d_in[12];
    const float* b_out = (const float*)d_in[13];
    float* out = (float*)d_out;
    float* ws = (float*)d_ws;

    // ws layout — cursor in FLOAT units; u16 buffers consume (u16_count/2) floats.
    constexpr size_t U_F    = 32 * 256;
    constexpr size_t V_F    = 128 * 256;
    constexpr size_t H3_F   = (size_t)ROWS_ * K3MLP_ / 2;
    constexpr size_t W3_F   = (size_t)256 * K3MLP_ / 2;
    constexpr size_t WO3_F  = (size_t)576 * K3MLP_ / 2;
    constexpr size_t RAW_F  = (size_t)ROWS_ * TC_;
    constexpr size_t AB3_F  = 2 * (size_t)ROWS_ * K3IR_ / 2;
    constexpr size_t TT3_F  = 2 * (size_t)256 * K3IR_ / 2;
    constexpr size_t EO_F   = 2 * (size_t)ROWS_ * 256;
    constexpr size_t SUMS_F = (size_t)B_ * NCH_ * NC_ * 2;

    size_t cur = 0;
    float* U    = ws + cur;                 cur += U_F;
    float* V    = ws + cur;                 cur += V_F;
    u16*  H1_3  = (u16*)(ws + cur);         cur += H3_F;
    u16*  H2_3  = (u16*)(ws + cur);         cur += H3_F;
    u16*  H3_3  = (u16*)(ws + cur);         cur += H3_F;
    u16*  W1_3  = (u16*)(ws + cur);         cur += W3_F;
    u16*  W2_3  = (u16*)(ws + cur);         cur += W3_F;
    u16*  WO_3  = (u16*)(ws + cur);         cur += WO3_F;
    float* RAW  = ws + cur;                 cur += RAW_F;
    u16*  AB3   = (u16*)(ws + cur);         cur += AB3_F;
    u16*  AB3e  = AB3;
    u16*  AB3o  = AB3 + (size_t)ROWS_ * K3IR_;
    u16*  Tt3   = (u16*)(ws + cur);         cur += TT3_F;
    float* EO   = ws + cur;                 cur += EO_F;
    double* SUMS = (double*)(ws + cur);     cur += SUMS_F;
    int*   CNT  = (int*)(ws + cur);         cur += 512;
    float2* TAPS = (float2*)(ws + cur);     // 512*128 float2

    // 1) fused prep: tables + weight triplets + taps + U + V (gemm2 absorbed)
    prep_kernel<<<3552, 256, 0, stream>>>(param, proj_w, proj_b, pos, w0, w1, w2, w_out,
                                          times, Tt3, W1_3, W2_3, WO_3, CNT, TAPS, U, V);
    // 2) fuse1: H1_3 = lrelu(U[b]+V[f]+b0) triplet
    fuse1_kernel<<<ROWS_ * CH_ / 256, 256, 0, stream>>>(U, V, b0, H1_3);
    // 3) MLP layers 2,3 (bf16-split MFMA, 32x64 tiles, 2+ blocks/CU)
    mfgemm<0, K3MLP_><<<dim3(4, 128, 1), 128, 0, stream>>>(H1_3, W1_3, b1, H2_3, 256,
                                                           K3MLP_, K3MLP_, K3MLP_, 0, 0, 0);
    mfgemm<0, K3MLP_><<<dim3(4, 128, 1), 128, 0, stream>>>(H2_3, W2_3, b2, H3_3, 256,
                                                           K3MLP_, K3MLP_, K3MLP_, 0, 0, 0);
    // 4) output layer -> RAW fp32 (bias, N=514 guarded)
    mfgemm<1, K3MLP_><<<dim3(9, 128, 1), 128, 0, stream>>>(H3_3, WO_3, b_out, RAW, TC_,
                                                           K3MLP_, K3MLP_, TC_, 0, 0, 0);
    // 5) phase scan (double carry) -> AB3 triplets (pads by spare threads)
    dim3 gS(B_, NCH_);
    scan1_kernel<<<gS, 320, 0, stream>>>(RAW, noise, SUMS);
    scan2_kernel<<<gS, 320, 0, stream>>>(RAW, noise, SUMS, AB3e, AB3o);
    // 6) parity irfft (z-batched): EO[z] = AB3[z] @ Tt3[z]^T
    mfgemm<2, K3IR_><<<dim3(4, 128, 2), 128, 0, stream>>>(AB3, Tt3, nullptr, EO, 256,
                                                          K3IR_, K3IR_, 256,
                                                          (size_t)ROWS_ * K3IR_,
                                                          (size_t)256 * K3IR_,
                                                          (size_t)ROWS_ * 256);
    // 7) sparse conv with inline overlap-add/hann -> out
    dim3 gC(NS_ / 2048, B_ * NE_);
    conv2_kernel<<<gC, 256, 0, stream>>>(EO, EO + (size_t)ROWS_ * 256, CNT, TAPS, out);
}

// Round 10
// 95.107 us; speedup vs baseline: 2.7725x; 1.1187x over previous
//
#include <hip/hip_runtime.h>
#include <cstddef>

typedef unsigned short u16;
typedef __bf16 bf16x8 __attribute__((ext_vector_type(8)));
typedef float f32x4 __attribute__((ext_vector_type(4)));

// Problem constants
constexpr int B_   = 32;
constexpr int CTX_ = 128;
constexpr int NF_  = 128;     // frames
constexpr int NS_  = 32768;   // samples
constexpr int NE_  = 16;      // events
constexpr int CH_  = 256;
constexpr int NC_  = 257;     // coeffs
constexpr int TC_  = 514;     // 2*coeffs
constexpr int ROWS_ = B_ * NF_;  // 4096
constexpr int CHUNK_ = 8;        // frames per scan chunk
constexpr int NCH_ = NF_ / CHUNK_;  // 16 chunks
constexpr int K3MLP_ = 768;      // 3*256 (logical triplet K)
constexpr int SEGM_ = 256;       // MLP pair-plane width
constexpr int K3IR_ = 960;       // 3*320 (logical triplet K, irfft)
constexpr int SEGI_ = 320;       // irfft pair-plane width (content 258/256 + zeros)
constexpr int PIRW_ = 2 * SEGI_; // 640 u16 per AB row
constexpr int PMLW_ = 2 * SEGM_; // 512 u16 per H/W row
constexpr float PI_ = 3.14159265358979323846f;

__device__ __forceinline__ float lrelu(float v) { return v > 0.f ? v : 0.2f * v; }
__device__ __forceinline__ u16 f2bf(float x) {
    unsigned u = __float_as_uint(x);
    return (u16)((u + 0x7FFFu + ((u >> 16) & 1u)) >> 16);
}
__device__ __forceinline__ float bf2f(u16 h) { return __uint_as_float(((unsigned)h) << 16); }

// ============ prep: table(pair,LUT) | weights(pair) | compact | U | V ============
// [0,1280): irfft pair table  [1280,2368): weight pairs
// [2368,2880): tap compaction [2880,2912): U rows  [2912,3040): V rows
__global__ __launch_bounds__(256) void prep_kernel(
    const float* __restrict__ param, const float* __restrict__ pw,
    const float* __restrict__ pb, const float* __restrict__ pos,
    const float* __restrict__ w0, const float* __restrict__ w1,
    const float* __restrict__ w2, const float* __restrict__ wo,
    const float* __restrict__ times,
    u16* __restrict__ Tt, u16* __restrict__ W1p, u16* __restrict__ W2p,
    u16* __restrict__ WOp, int* __restrict__ cnt, float2* __restrict__ taps,
    float* __restrict__ U, float* __restrict__ V)
{
    int blk = blockIdx.x;
    int tid = threadIdx.x;
    if (blk < 1280) {
        // ---- irfft pair table via 512-entry cos LUT ----
        __shared__ float lut[512];
        lut[tid]       = cosf((float)tid * (PI_ / 256.f));
        lut[tid + 256] = cosf((float)(tid + 256) * (PI_ / 256.f));
        __syncthreads();
        int idx = blk * 256 + tid;              // < 2*256*640
        int z = idx / (256 * PIRW_);
        int r = idx - z * (256 * PIRW_);
        int n = r / PIRW_, c = r - n * PIRW_;
        bool hiplane = c < SEGI_;
        int j = hiplane ? c : c - SEGI_;
        float val = 0.f;
        if (z == 0) {
            if (j < 129) {
                int k = 2 * j;
                float w = (k == 0 || k == 256) ? 1.f : 2.f;
                int m = (k * n) & 511;
                val = w * (1.f / 512.f) * lut[m];
            } else if (j < 258) {
                int kk = 2 * (j - 129);
                float w = (kk == 0 || kk == 256) ? 1.f : 2.f;
                int m = (kk * n) & 511;
                val = -w * (1.f / 512.f) * lut[(m - 128) & 511];   // sin
            }
        } else {
            if (j < 128) {
                int k = 2 * j + 1;
                int m = (k * n) & 511;
                val = 2.f * (1.f / 512.f) * lut[m];
            } else if (j < 256) {
                int kk = 2 * (j - 128) + 1;
                int m = (kk * n) & 511;
                val = -2.f * (1.f / 512.f) * lut[(m - 128) & 511]; // sin
            }
        }
        u16 h = f2bf(val);
        Tt[idx] = hiplane ? h : f2bf(val - bf2f(h));
    } else if (blk < 2368) {
        // ---- weight pairs (hi|lo planar) ----
        int row = blk - 1280;        // 0..1087
        int k = tid;
        float v;
        u16* p;
        if (row < 256) {
            v = w1[row * 256 + k];
            p = W1p + (size_t)row * PMLW_;
        } else if (row < 512) {
            v = w2[(row - 256) * 256 + k];
            p = W2p + (size_t)(row - 256) * PMLW_;
        } else {
            int n = row - 512;       // 0..575, valid < 514
            v = (n < TC_) ? wo[n * 256 + k] : 0.f;
            p = WOp + (size_t)n * PMLW_;
        }
        u16 h = f2bf(v);
        p[k] = h; p[256 + k] = f2bf(v - bf2f(h));
    } else if (blk < 2880) {
        // ---- tap compaction ----
        int be = blk - 2368;
        __shared__ int c;
        if (tid == 0) c = 0;
        __syncthreads();
        if (tid < NF_) {
            float v = times[(size_t)be * NF_ + tid];
            if (v != 0.f) {
                int slot = atomicAdd(&c, 1);
                taps[(size_t)be * NF_ + slot] = make_float2((float)tid, v);
            }
        }
        __syncthreads();
        if (tid == 0) cnt[be] = c;
    } else if (blk < 2912) {
        // ---- U rows: recompute y0[b] in LDS, then U[b][n] = y0 . w0[n] ----
        int b = blk - 2880;      // 0..31
        __shared__ float ly[256];
        {
            const float* pr = param + b * CTX_;
            const float* wr = pw + tid * CTX_;
            float s = 0.f;
            #pragma unroll 4
            for (int j = 0; j < CTX_; ++j) s += pr[j] * wr[j];
            ly[tid] = s + pb[tid];
        }
        __syncthreads();
        {
            const float* wn = w0 + tid * CH_;
            float s = 0.f;
            #pragma unroll 4
            for (int c2 = 0; c2 < CH_; ++c2) s += ly[c2] * wn[c2];
            U[b * CH_ + tid] = s;
        }
    } else {
        // ---- V rows: V[f][n] = pos[f] . w0[n] ----
        int f = blk - 2912;      // 0..127
        const float* pf = pos + f * CH_;
        const float* wn = w0 + tid * CH_;
        float s = 0.f;
        #pragma unroll 4
        for (int c2 = 0; c2 < CH_; ++c2) s += pf[c2] * wn[c2];
        V[f * CH_ + tid] = s;
    }
}

// ---------------- fuse1: H1 pair = lrelu(U[b] + V[f] + b0) ----------------
__global__ void fuse1_kernel(const float* __restrict__ U, const float* __restrict__ V,
                             const float* __restrict__ b0, u16* __restrict__ Hp) {
    int idx = blockIdx.x * 256 + threadIdx.x;   // 4096*256
    int c = idx & 255;
    int row = idx >> 8;
    int b = row >> 7, f = row & 127;
    float v = lrelu(U[b * CH_ + c] + V[f * CH_ + c] + b0[c]);
    u16 h = f2bf(v);
    u16* p = Hp + (size_t)row * PMLW_;
    p[c] = h; p[256 + c] = f2bf(v - bf2f(h));
}

// ---------------- mfgemm: C = A3 @ B3^T, bf16-split MFMA on PAIR buffers ----------
// Logical triplet A=[Ah|Al|Ah], B=[Bh|Bh|Bl] with plane width SEG; global buffers
// store only [hi|lo]; prefetch offsets remapped at compile time:
//   kA(kt) = kt>=2*SEG ? kt-2*SEG : kt ;  kB(kt) = kt>=SEG ? kt-SEG : kt.
// 32x64 tile, 128 threads, depth-2 prefetch, double-buffered LDS (24KB).
// EPI 0: bias+lrelu -> bf16 pair (ldc=512); EPI 1: bias -> fp32 (N-guarded);
// EPI 2: plain fp32 (z-batched).
template<int EPI, int K3, int SEG>
__global__ __launch_bounds__(128) void mfgemm(
    const u16* __restrict__ A3, const u16* __restrict__ B3,
    const float* __restrict__ bias, void* __restrict__ Cout,
    int N, int lda, int ldb, int ldc,
    size_t sAz, size_t sBz, size_t sCz)
{
    constexpr int NSTEP = K3 / 64;
    A3 += (size_t)blockIdx.z * sAz;
    B3 += (size_t)blockIdx.z * sBz;
    const int tid = threadIdx.x;
    const int m0 = blockIdx.y * 32, n0 = blockIdx.x * 64;
    __shared__ __align__(16) u16 Als[2 * 32 * 64];   //  8KB
    __shared__ __align__(16) u16 Bls[2 * 64 * 64];   // 16KB
    const int sr = tid >> 2;
    const int sc = (tid & 3) * 16;
    const u16* ga  = A3 + (size_t)(m0 + sr) * lda + sc;
    const u16* gb0 = B3 + (size_t)(n0 + sr) * ldb + sc;
    const u16* gb1 = B3 + (size_t)(n0 + 32 + sr) * ldb + sc;
    const int xr = (sr & 7) << 4;
    const int loA0 = sr * 128 + ((sc * 2) ^ xr);
    const int loA1 = sr * 128 + ((sc * 2 + 16) ^ xr);
    const int loB2 = (sr + 32) * 128 + ((sc * 2) ^ xr);
    const int loB3 = (sr + 32) * 128 + ((sc * 2 + 16) ^ xr);
    const int wv = tid >> 6, lane = tid & 63;
    const int wc = wv * 32;
    const int lr = lane & 15;
    const int lkb = (lane >> 4) * 16;
    const int xf = (lr & 7) << 4;
    const int raf0 = lr * 128, raf1 = (16 + lr) * 128;
    const int rbf0 = (wc + lr) * 128, rbf1 = (wc + 16 + lr) * 128;
    f32x4 acc00 = {0.f, 0.f, 0.f, 0.f}, acc01 = acc00, acc10 = acc00, acc11 = acc00;

    uint4 pa0, pa1, pb0, pb1, pb2, pb3;   // set P
    uint4 qa0, qa1, qb0, qb1, qb2, qb3;   // set Q
    auto kA = [](int kt) { return kt >= 2 * SEG ? kt - 2 * SEG : kt; };
    auto kB = [](int kt) { return kt >= SEG ? kt - SEG : kt; };
    auto loadP = [&](int kt) {
        int a = kA(kt), b = kB(kt);
        pa0 = *(const uint4*)(ga + a);  pa1 = *(const uint4*)(ga + a + 8);
        pb0 = *(const uint4*)(gb0 + b); pb1 = *(const uint4*)(gb0 + b + 8);
        pb2 = *(const uint4*)(gb1 + b); pb3 = *(const uint4*)(gb1 + b + 8);
    };
    auto loadQ = [&](int kt) {
        int a = kA(kt), b = kB(kt);
        qa0 = *(const uint4*)(ga + a);  qa1 = *(const uint4*)(ga + a + 8);
        qb0 = *(const uint4*)(gb0 + b); qb1 = *(const uint4*)(gb0 + b + 8);
        qb2 = *(const uint4*)(gb1 + b); qb3 = *(const uint4*)(gb1 + b + 8);
    };
    auto compute = [&](int p) {
        const char* pa = (const char*)Als + p * 4096;
        const char* pb = (const char*)Bls + p * 8192;
        #pragma unroll
        for (int s = 0; s < 2; ++s) {
            int kb = (s * 64 + lkb) ^ xf;
            bf16x8 a0 = *(const bf16x8*)(pa + raf0 + kb);
            bf16x8 a1 = *(const bf16x8*)(pa + raf1 + kb);
            bf16x8 b0 = *(const bf16x8*)(pb + rbf0 + kb);
            bf16x8 b1 = *(const bf16x8*)(pb + rbf1 + kb);
            acc00 = __builtin_amdgcn_mfma_f32_16x16x32_bf16(a0, b0, acc00, 0, 0, 0);
            acc01 = __builtin_amdgcn_mfma_f32_16x16x32_bf16(a0, b1, acc01, 0, 0, 0);
            acc10 = __builtin_amdgcn_mfma_f32_16x16x32_bf16(a1, b0, acc10, 0, 0, 0);
            acc11 = __builtin_amdgcn_mfma_f32_16x16x32_bf16(a1, b1, acc11, 0, 0, 0);
        }
    };
    auto stage = [&](int p, const uint4& a0, const uint4& a1, const uint4& b0,
                     const uint4& b1, const uint4& b2, const uint4& b3) {
        char* ab = (char*)Als + p * 4096;
        char* bb = (char*)Bls + p * 8192;
        *(uint4*)(ab + loA0) = a0; *(uint4*)(ab + loA1) = a1;
        *(uint4*)(bb + loA0) = b0; *(uint4*)(bb + loA1) = b1;
        *(uint4*)(bb + loB2) = b2; *(uint4*)(bb + loB3) = b3;
    };
    loadP(0);
    if (NSTEP > 1) loadQ(64);
    int p = 0;
    #pragma unroll
    for (int i = 0; i < NSTEP; ++i) {
        if ((i & 1) == 0) {
            stage(p, pa0, pa1, pb0, pb1, pb2, pb3);
            __syncthreads();
            if (i + 2 < NSTEP) loadP((i + 2) * 64);
            compute(p);
        } else {
            stage(p, qa0, qa1, qb0, qb1, qb2, qb3);
            __syncthreads();
            if (i + 2 < NSTEP) loadQ((i + 2) * 64);
            compute(p);
        }
        p ^= 1;
    }
    const int er = (lane >> 4) * 4;
    const int ec = lane & 15;
    auto emit = [&](const f32x4& A, int mi, int ni) {
        #pragma unroll
        for (int r = 0; r < 4; ++r) {
            int m = m0 + mi * 16 + er + r;
            int n = n0 + wc + ni * 16 + ec;
            float v = A[r];
            if (EPI == 0) {
                v = lrelu(v + bias[n]);
                u16 h = f2bf(v);
                u16* p2 = (u16*)Cout + (size_t)m * ldc + n;
                p2[0] = h; p2[256] = f2bf(v - bf2f(h));
            } else if (EPI == 1) {
                if (n < N) ((float*)Cout)[(size_t)m * ldc + n] = v + bias[n];
            } else {
                float* cf = (float*)Cout + (size_t)blockIdx.z * sCz;
                cf[(size_t)m * ldc + n] = v;
            }
        }
    };
    emit(acc00, 0, 0); emit(acc01, 0, 1); emit(acc10, 1, 0); emit(acc11, 1, 1);
}

// ---------------- scan pass 1: per-chunk sum of dphi (double) ----------------
__global__ void scan1_kernel(const float* __restrict__ raw, const float* __restrict__ noise,
                             double* __restrict__ sums) {
    int b = blockIdx.x, c = blockIdx.y;
    int k = threadIdx.x;
    if (k >= NC_) return;
    float kf = (float)k * (PI_ / 256.f);
    double s = 0.0;
    #pragma unroll
    for (int j = 0; j < CHUNK_; ++j) {
        int row = b * NF_ + c * CHUNK_ + j;
        float2 v = *(const float2*)(raw + (size_t)row * TC_ + 2 * k);
        float d = (1.f + v.y * noise[(size_t)row * NC_ + k]) * kf;
        s += (double)d;
    }
    sums[((size_t)(b * NCH_ + c)) * NC_ + k] = s;
}

// ---------------- scan pass 2: prefix + sincos -> parity PAIR planes; pads inline -----
// ABe/ABo rows: [hi(320) | lo(320)] u16; cos coeff at kpos=half, sin at scol.
__global__ void scan2_kernel(const float* __restrict__ raw, const float* __restrict__ noise,
                             const double* __restrict__ sums,
                             u16* __restrict__ ABe, u16* __restrict__ ABo) {
    int b = blockIdx.x, c = blockIdx.y;
    int k = threadIdx.x;
    if (k >= NC_) {
        // zero pad columns: even: hi[258,320)+lo[258,320); odd: hi[256,320)+lo[256,320)
        int t = k - NC_;   // 0..62
        for (int idx = t; idx < 252; idx += 63) {
            int col;
            u16* base;
            if (idx < 62)       { col = 258 + idx;              base = ABe; }
            else if (idx < 124) { col = SEGI_ + 258 + (idx - 62);  base = ABe; }
            else if (idx < 188) { col = 256 + (idx - 124);       base = ABo; }
            else                { col = SEGI_ + 256 + (idx - 188); base = ABo; }
            for (int j = 0; j < CHUNK_; ++j)
                base[(size_t)(b * NF_ + c * CHUNK_ + j) * PIRW_ + col] = 0;
        }
        return;
    }
    double p = 0.0;
    for (int cc = 0; cc < c; ++cc)
        p += sums[((size_t)(b * NCH_ + cc)) * NC_ + k];
    float kf = (float)k * (PI_ / 256.f);
    int half = k >> 1;
    bool even = (k & 1) == 0;
    int ccol = half;
    int scol = even ? (129 + half) : (128 + half);
    u16* dst = even ? ABe : ABo;
    for (int j = 0; j < CHUNK_; ++j) {
        int row = b * NF_ + c * CHUNK_ + j;
        float2 v = *(const float2*)(raw + (size_t)row * TC_ + 2 * k);
        float d = (1.f + v.y * noise[(size_t)row * NC_ + k]) * kf;
        p += (double)d;
        float m = fabsf(v.x);
        float sn, cs;
        sincosf((float)p, &sn, &cs);
        float a = m * cs, bb = m * sn;
        u16* pr = dst + (size_t)row * PIRW_;
        u16 ha = f2bf(a);
        pr[ccol] = ha; pr[SEGI_ + ccol] = f2bf(a - bf2f(ha));
        u16 hb = f2bf(bb);
        pr[scol] = hb; pr[SEGI_ + scol] = f2bf(bb - bf2f(hb));
    }
}

// ---------------- conv2: sparse conv with inline OLA (sig computed from E/O) ---------
__global__ __launch_bounds__(256) void conv2_kernel(const float* __restrict__ E,
                                                    const float* __restrict__ O,
                                                    const int* __restrict__ cnt,
                                                    const float2* __restrict__ taps,
                                                    float* __restrict__ out) {
    int be = blockIdx.y;
    int b = be >> 4;
    int n = cnt[be];
    int t = blockIdx.x * 2048 + (int)threadIdx.x * 8;
    int r0 = t & 255;
    float hr[8], hr2[8];
    #pragma unroll
    for (int j = 0; j < 8; ++j) {
        float cj = cosf((float)(r0 + j) * (PI_ / 256.f));
        hr[j]  = 0.5f - 0.5f * cj;
        hr2[j] = 0.5f + 0.5f * cj;
    }
    float acc[8] = {};
    for (int i = 0; i < n; ++i) {
        float2 ka = taps[(size_t)be * NF_ + i];
        int s0 = t - ((int)ka.x << 8);
        if (s0 < 0) continue;
        float amp = ka.y;
        int q = s0 >> 8;
        size_t row = (size_t)(b * NF_ + q) * 256 + r0;
        float4 e0 = *(const float4*)(E + row);
        float4 e1 = *(const float4*)(E + row + 4);
        float4 o0 = *(const float4*)(O + row);
        float4 o1 = *(const float4*)(O + row + 4);
        float sv[8];
        sv[0] = hr[0] * (e0.x + o0.x); sv[1] = hr[1] * (e0.y + o0.y);
        sv[2] = hr[2] * (e0.z + o0.z); sv[3] = hr[3] * (e0.w + o0.w);
        sv[4] = hr[4] * (e1.x + o1.x); sv[5] = hr[5] * (e1.y + o1.y);
        sv[6] = hr[6] * (e1.z + o1.z); sv[7] = hr[7] * (e1.w + o1.w);
        if (q > 0) {
            float4 pe0 = *(const float4*)(E + row - 256);
            float4 pe1 = *(const float4*)(E + row - 252);
            float4 po0 = *(const float4*)(O + row - 256);
            float4 po1 = *(const float4*)(O + row - 252);
            sv[0] += hr2[0] * (pe0.x - po0.x); sv[1] += hr2[1] * (pe0.y - po0.y);
            sv[2] += hr2[2] * (pe0.z - po0.z); sv[3] += hr2[3] * (pe0.w - po0.w);
            sv[4] += hr2[4] * (pe1.x - po1.x); sv[5] += hr2[5] * (pe1.y - po1.y);
            sv[6] += hr2[6] * (pe1.z - po1.z); sv[7] += hr2[7] * (pe1.w - po1.w);
        }
        #pragma unroll
        for (int j = 0; j < 8; ++j) acc[j] += amp * sv[j];
    }
    float* op = out + (size_t)be * NS_ + t;
    *(float4*)op = make_float4(acc[0], acc[1], acc[2], acc[3]);
    *(float4*)(op + 4) = make_float4(acc[4], acc[5], acc[6], acc[7]);
}

extern "C" void kernel_launch(void* const* d_in, const int* in_sizes, int n_in,
                              void* d_out, int out_size, void* d_ws, size_t ws_size,
                              hipStream_t stream) {
    const float* param  = (const float*)d_in[0];
    const float* times  = (const float*)d_in[1];
    const float* noise  = (const float*)d_in[2];
    const float* pos    = (const float*)d_in[3];
    const float* proj_w = (const float*)d_in[4];
    const float* proj_b = (const float*)d_in[5];
    const float* w0 = (const float*)d_in[6];
    const float* b0 = (const float*)d_in[7];
    const float* w1 = (const float*)d_in[8];
    const float* b1 = (const float*)d_in[9];
    const float* w2 = (const float*)d_in[10];
    const float* b2 = (const float*)d_in[11];
    const float* w_out = (const float*)d_in[12];
    const float* b_out = (const float*)d_in[13];
    float* out = (float*)d_out;
    float* ws = (float*)d_ws;

    // ws layout — cursor in FLOAT units; u16 buffers consume (u16_count/2) floats.
    constexpr size_t U_F    = 32 * 256;
    constexpr size_t V_F    = 128 * 256;
    constexpr size_t HP_F   = (size_t)ROWS_ * PMLW_ / 2;    // 1,048,576 per buffer
    constexpr size_t W_F    = (size_t)256 * PMLW_ / 2;      //    65,536
    constexpr size_t WO_F   = (size_t)576 * PMLW_ / 2;      //   147,456
    constexpr size_t RAW_F  = (size_t)ROWS_ * TC_;          // 2,105,344
    constexpr size_t ABP_F  = 2 * (size_t)ROWS_ * PIRW_ / 2;// 2,621,440
    constexpr size_t TTP_F  = 2 * (size_t)256 * PIRW_ / 2;  //   163,840
    constexpr size_t EO_F   = 2 * (size_t)ROWS_ * 256;      // 2,097,152
    constexpr size_t SUMS_F = (size_t)B_ * NCH_ * NC_ * 2;  //   263,168

    size_t cur = 0;
    float* U    = ws + cur;                 cur += U_F;
    float* V    = ws + cur;                 cur += V_F;
    u16*  H1p   = (u16*)(ws + cur);         cur += HP_F;
    u16*  H2p   = (u16*)(ws + cur);         cur += HP_F;
    u16*  H3p   = (u16*)(ws + cur);         cur += HP_F;
    u16*  W1p   = (u16*)(ws + cur);         cur += W_F;
    u16*  W2p   = (u16*)(ws + cur);         cur += W_F;
    u16*  WOp   = (u16*)(ws + cur);         cur += WO_F;
    float* RAW  = ws + cur;                 cur += RAW_F;
    u16*  ABP   = (u16*)(ws + cur);         cur += ABP_F;
    u16*  ABe   = ABP;
    u16*  ABo   = ABP + (size_t)ROWS_ * PIRW_;
    u16*  TTP   = (u16*)(ws + cur);         cur += TTP_F;
    float* EO   = ws + cur;                 cur += EO_F;
    double* SUMS = (double*)(ws + cur);     cur += SUMS_F;
    int*   CNT  = (int*)(ws + cur);         cur += 512;
    float2* TAPS = (float2*)(ws + cur);     // 512*128 float2

    // 1) fused prep: pair table (LUT) + weight pairs + taps + U + V
    prep_kernel<<<3040, 256, 0, stream>>>(param, proj_w, proj_b, pos, w0, w1, w2, w_out,
                                          times, TTP, W1p, W2p, WOp, CNT, TAPS, U, V);
    // 2) fuse1: H1 pair = lrelu(U[b]+V[f]+b0)
    fuse1_kernel<<<ROWS_ * CH_ / 256, 256, 0, stream>>>(U, V, b0, H1p);
    // 3) MLP layers 2,3 (bf16-split MFMA on pair buffers)
    mfgemm<0, K3MLP_, SEGM_><<<dim3(4, 128, 1), 128, 0, stream>>>(H1p, W1p, b1, H2p, 256,
                                                                  PMLW_, PMLW_, PMLW_, 0, 0, 0);
    mfgemm<0, K3MLP_, SEGM_><<<dim3(4, 128, 1), 128, 0, stream>>>(H2p, W2p, b2, H3p, 256,
                                                                  PMLW_, PMLW_, PMLW_, 0, 0, 0);
    // 4) output layer -> RAW fp32 (bias, N=514 guarded)
    mfgemm<1, K3MLP_, SEGM_><<<dim3(9, 128, 1), 128, 0, stream>>>(H3p, WOp, b_out, RAW, TC_,
                                                                  PMLW_, PMLW_, TC_, 0, 0, 0);
    // 5) phase scan (double carry) -> AB pair planes (pads by spare threads)
    dim3 gS(B_, NCH_);
    scan1_kernel<<<gS, 320, 0, stream>>>(RAW, noise, SUMS);
    scan2_kernel<<<gS, 320, 0, stream>>>(RAW, noise, SUMS, ABe, ABo);
    // 6) parity irfft (z-batched): EO[z] = AB[z] @ Tt[z]^T
    mfgemm<2, K3IR_, SEGI_><<<dim3(4, 128, 2), 128, 0, stream>>>(ABP, TTP, nullptr, EO, 256,
                                                                 PIRW_, PIRW_, 256,
                                                                 (size_t)ROWS_ * PIRW_,
                                                                 (size_t)256 * PIRW_,
                                                                 (size_t)ROWS_ * 256);
    // 7) sparse conv with inline overlap-add/hann -> out
    dim3 gC(NS_ / 2048, B_ * NE_);
    conv2_kernel<<<gC, 256, 0, stream>>>(EO, EO + (size_t)ROWS_ * 256, CNT, TAPS, out);
}